// Round 1
// baseline (1955.781 us; speedup 1.0000x reference)
//
#include <hip/hip_runtime.h>
#include <math.h>

// ---------------------------------------------------------------------------
// DyRes/CondConv AlexNet forward. R8: register-prefetch double-buffering in
// mgemm (T14 async-STAGE split: issue next K-step's global loads into regs
// before the compute phase; ds_write them after the next barrier) + B hi/lo
// split moved from the compute loop into staging (Bh/Bl bf16 planes in LDS,
// compute loop is pure ds_read_b128 + MFMA). __launch_bounds__(256,3) pins
// regalloc at 3 waves/SIMD so prefetch regs don't drop occupancy.
// Tile 128Mx128N (4 waves, 64x64 each), BK=32, split-K fp32 atomics.
// ---------------------------------------------------------------------------

typedef unsigned short u16;
typedef unsigned int u32;
typedef short bf16x8 __attribute__((ext_vector_type(8)));
typedef float f32x4 __attribute__((ext_vector_type(4)));

__device__ __forceinline__ u16 bf16_rne(float f) {
    u32 u = __float_as_uint(f);
    return (u16)((u + 0x7fffu + ((u >> 16) & 1u)) >> 16);
}
__device__ __forceinline__ u32 packsplit(float v) {
    u16 h = bf16_rne(v);
    float hf = __uint_as_float((u32)h << 16);
    u16 l = bf16_rne(v - hf);
    return ((u32)h << 16) | l;
}
__device__ __forceinline__ float unpackf(u32 p) {
    return __uint_as_float(p & 0xffff0000u) + __uint_as_float(p << 16);
}

// fp32 weights -> K-padded bf16 hi/lo planes (zero-padded beyond Kper)
__global__ __launch_bounds__(256)
void wsplit_kernel(const float* __restrict__ W, u16* __restrict__ whi,
                   u16* __restrict__ wlo, int total, int Kper, int Kpad)
{
    int idx = blockIdx.x * 256 + threadIdx.x;
    if (idx >= total) return;
    int r = idx / Kpad, k = idx - r * Kpad;
    float v = (k < Kper) ? W[(size_t)r * Kper + k] : 0.f;
    u16 h = bf16_rne(v);
    whi[idx] = h;
    wlo[idx] = bf16_rne(v - __uint_as_float((u32)h << 16));
}

__global__ __launch_bounds__(64)
void stats_kernel(const void* __restrict__ actv, float* __restrict__ s,
                  int Bsz, int C, int HW, int cbhw, int use_std, int packed)
{
    int idx = blockIdx.x;           // b*C + c
    int b = idx / C, c = idx - b * C;
    size_t base = (cbhw ? ((size_t)c * Bsz + b) : ((size_t)b * C + c)) * HW;
    int lane = threadIdx.x;
    float sum = 0.f, sq = 0.f;
    if (packed) {
        const u32* p = (const u32*)actv + base;
        for (int i = lane; i < HW; i += 64) { float v = unpackf(p[i]); sum += v; sq += v * v; }
    } else {
        const float* p = (const float*)actv + base;
        for (int i = lane; i < HW; i += 64) { float v = p[i]; sum += v; sq += v * v; }
    }
#pragma unroll
    for (int off = 32; off > 0; off >>= 1) {
        sum += __shfl_down(sum, off);
        sq  += __shfl_down(sq, off);
    }
    if (lane == 0) {
        float inv = 1.f / (float)HW;
        float mean = sum * inv;
        float var = sq * inv - mean * mean;
        float outv = mean;
        if (use_std) outv += sqrtf(fmaxf(var, 0.f));
        s[idx] = outv;
    }
}

__global__ __launch_bounds__(64)
void routing_kernel(const float* __restrict__ s, const float* __restrict__ rw,
                    const float* __restrict__ rb, float* __restrict__ r,
                    int C, int softmax_mode)
{
    int b = blockIdx.x;
    int lane = threadIdx.x;
    float d0 = 0.f, d1 = 0.f, d2 = 0.f;
    for (int c = lane; c < C; c += 64) {
        float sv = s[b * C + c];
        d0 += sv * rw[c];
        d1 += sv * rw[C + c];
        d2 += sv * rw[2 * C + c];
    }
#pragma unroll
    for (int off = 32; off > 0; off >>= 1) {
        d0 += __shfl_down(d0, off);
        d1 += __shfl_down(d1, off);
        d2 += __shfl_down(d2, off);
    }
    if (lane == 0) {
        d0 += rb[0]; d1 += rb[1]; d2 += rb[2];
        if (softmax_mode) {
            float mx = fmaxf(d0, fmaxf(d1, d2));
            float e0 = expf(d0 - mx), e1 = expf(d1 - mx), e2 = expf(d2 - mx);
            float inv = 1.f / (e0 + e1 + e2);
            r[b * 3 + 0] = e0 * inv;
            r[b * 3 + 1] = e1 * inv;
            r[b * 3 + 2] = e2 * inv;
        } else {
            r[b * 3 + 0] = 1.f / (1.f + expf(-d0));
            r[b * 3 + 1] = 1.f / (1.f + expf(-d1));
            r[b * 3 + 2] = 1.f / (1.f + expf(-d2));
        }
    }
}

// padded im2col k-decode: kk in [0, 3*Kpad); pad entries get OOB sentinel kh=15
__global__ __launch_bounds__(256)
void ktab_kernel(int2* __restrict__ tab, int Kpad, int Kper, int chanStride, int W)
{
    int kk = blockIdx.x * 256 + threadIdx.x;
    if (kk >= 3 * Kpad) return;
    int e = kk / Kpad;
    int kq = kk - e * Kpad;
    if (kq >= Kper) { tab[kk] = make_int2(0, 15 << 4); return; }
    int ci = kq / 9;
    int r9 = kq - ci * 9;
    int kh = r9 / 3;
    int kw = r9 - kh * 3;
    tab[kk] = make_int2(ci * chanStride + kh * W + kw, (kh << 4) | (kw << 2));
}

// ---------------------------------------------------------------------------
// MFMA GEMM, 128Mx128N tile, BK=32, 4 waves (2x2), wave tile 64x64.
// A from pre-split bf16 hi/lo planes: row (eA*M+m), k stride Kpad (zero-padded).
// B packed u32 source: BMODE 0 plain [n][Kpad]; 1 gather [Ci,B,H,W]; 2 gather
// [B,Ci,H,W]. B is split to bf16 hi/lo planes AT STAGE TIME (compute loop is
// pure ds_read_b128 + MFMA). K-loop is register-prefetch double-buffered:
//   store(regs)->sync->issue loads(kq+32)->compute->sync
// so gather/plane-load latency hides under the MFMA phase.
// z: expert chunk = bz/zpe (zpe chunks per expert; FCs pass zpe=gridDim.z -> e=0).
// Products: al*bh + ah*bl + ah*bh, fp32 acc; epilogue r-scale (convs), bias
// (bz==0), fp32 atomicAdd into pre-zeroed Cout.
// ---------------------------------------------------------------------------
template<int BMODE, int BIAS, int TROUT>
__global__ __launch_bounds__(256, 3)
void mgemm_kernel(const u16* __restrict__ Whi, const u16* __restrict__ Wlo,
                  const u32* __restrict__ Bpk, const int2* __restrict__ ktab,
                  const float* __restrict__ rptr, const float* __restrict__ bias,
                  float* __restrict__ Cout,
                  int M, int N, int Kpad, int Kchunk, int zpe,
                  int Ci, int Bsz, int H, int W, int lgS, int lgOW, int stride)
{
    __shared__ __align__(16) u16 Ah[128 * 40], Al[128 * 40];  // rows m, pad to 40
    __shared__ __align__(16) u16 Bh[128 * 40], Bl[128 * 40];  // rows n, pad to 40
    const int tid = threadIdx.x;
    const int n0 = blockIdx.x << 7, m0 = blockIdx.y << 7;
    const int bz = blockIdx.z;
    const int eA = bz / zpe;
    const int kq0 = (bz - eA * zpe) * Kchunk;

    // staging coords
    const int rowA = tid >> 1, kh16 = (tid & 1) << 4;   // A: 2 thr/row, 16 bf16 each
    const int nB = tid & 127, kOff = (tid >> 7) << 4;   // B: 16 k-elements per thread

    // n-side conv indices (k-independent)
    int ohs = 0, ows = 0; long nBase = 0;
    if (BMODE != 0) {
        int nn = n0 + nB;
        int bB = nn >> lgS;
        int sidx = nn & ((1 << lgS) - 1);
        ohs = (sidx >> lgOW) * stride - 1;
        ows = (sidx & ((1 << lgOW) - 1)) * stride - 1;
        long bOff = (BMODE == 2) ? (long)bB * Ci * H * W : (long)bB * H * W;
        nBase = bOff + (long)ohs * W + ows;
    }

    const int lane = tid & 63, wv = tid >> 6;
    const int lm = lane & 15, qd = lane >> 4;
    const int wm = (wv & 1) << 6, wn = (wv >> 1) << 6;

    f32x4 acc[4][4];
#pragma unroll
    for (int i = 0; i < 4; ++i)
#pragma unroll
        for (int j = 0; j < 4; ++j)
            acc[i][j] = (f32x4){0.f, 0.f, 0.f, 0.f};

    const size_t aRowBase = (size_t)eA * M;
    const int mg = m0 + rowA;
    const u16* hpBase = Whi + (aRowBase + mg) * Kpad + kh16;
    const u16* lpBase = Wlo + (aRowBase + mg) * Kpad + kh16;
    const int ktBase = eA * Kpad + kOff;

    // prefetch registers (statically indexed everywhere -> stay in VGPRs)
    uint4 pA0, pA1, pA2, pA3;   // A: hi x2, lo x2
    u32 pB[16];                 // B: packed u32, k = kOff..kOff+15

    auto LOAD_B = [&](int kq) {
        if (BMODE == 0) {
            const u32* bp = Bpk + (size_t)(n0 + nB) * Kpad + kq + kOff;
            uint4 q0 = *(const uint4*)bp;
            uint4 q1 = *(const uint4*)(bp + 4);
            uint4 q2 = *(const uint4*)(bp + 8);
            uint4 q3 = *(const uint4*)(bp + 12);
            pB[0] = q0.x;  pB[1] = q0.y;  pB[2]  = q0.z;  pB[3]  = q0.w;
            pB[4] = q1.x;  pB[5] = q1.y;  pB[6]  = q1.z;  pB[7]  = q1.w;
            pB[8] = q2.x;  pB[9] = q2.y;  pB[10] = q2.z;  pB[11] = q2.w;
            pB[12] = q3.x; pB[13] = q3.y; pB[14] = q3.z;  pB[15] = q3.w;
        } else {
#pragma unroll
            for (int j = 0; j < 16; ++j) {
                int2 t = ktab[ktBase + kq + j];
                int ih = ohs + (t.y >> 4), iw = ows + ((t.y >> 2) & 3);
                u32 p = 0;
                if ((unsigned)ih < (unsigned)H && (unsigned)iw < (unsigned)W)
                    p = Bpk[nBase + t.x];
                pB[j] = p;
            }
        }
    };
    auto LOAD_A = [&](int kq) {
        if (mg < M) {
            const u16* hp = hpBase + kq;
            const u16* lp = lpBase + kq;
            pA0 = *(const uint4*)hp; pA1 = *(const uint4*)(hp + 8);
            pA2 = *(const uint4*)lp; pA3 = *(const uint4*)(lp + 8);
        } else {
            pA0 = make_uint4(0, 0, 0, 0); pA1 = make_uint4(0, 0, 0, 0);
            pA2 = make_uint4(0, 0, 0, 0); pA3 = make_uint4(0, 0, 0, 0);
        }
    };
    auto STORE = [&]() {
        *(uint4*)(&Ah[rowA * 40 + kh16])     = pA0;
        *(uint4*)(&Ah[rowA * 40 + kh16 + 8]) = pA1;
        *(uint4*)(&Al[rowA * 40 + kh16])     = pA2;
        *(uint4*)(&Al[rowA * 40 + kh16 + 8]) = pA3;
        u32 hw[8], lw[8];
#pragma unroll
        for (int j = 0; j < 8; ++j) {
            u32 p0 = pB[2 * j], p1 = pB[2 * j + 1];
            hw[j] = (p0 >> 16) | (p1 & 0xffff0000u);
            lw[j] = (p0 & 0xffffu) | (p1 << 16);
        }
        *(uint4*)(&Bh[nB * 40 + kOff])     = make_uint4(hw[0], hw[1], hw[2], hw[3]);
        *(uint4*)(&Bh[nB * 40 + kOff + 8]) = make_uint4(hw[4], hw[5], hw[6], hw[7]);
        *(uint4*)(&Bl[nB * 40 + kOff])     = make_uint4(lw[0], lw[1], lw[2], lw[3]);
        *(uint4*)(&Bl[nB * 40 + kOff + 8]) = make_uint4(lw[4], lw[5], lw[6], lw[7]);
    };

    const int kEnd = kq0 + Kchunk;
    LOAD_B(kq0);
    LOAD_A(kq0);
    for (int kq = kq0; kq < kEnd; kq += 32) {
        // drain-in: write prefetched regs to LDS (compiler inserts vmcnt here)
        STORE();
        __syncthreads();
        // issue next K-step's loads; they stay in flight across the compute
        // phase and the trailing barrier (register dests are not drained).
        if (kq + 32 < kEnd) { LOAD_B(kq + 32); LOAD_A(kq + 32); }
        // ---- compute: pure ds_read_b128 + MFMA ----
        {
            bf16x8 ah[4], al[4];
#pragma unroll
            for (int mi = 0; mi < 4; ++mi) {
                int row = wm + mi * 16 + lm;
                ah[mi] = *(const bf16x8*)(&Ah[row * 40 + qd * 8]);
                al[mi] = *(const bf16x8*)(&Al[row * 40 + qd * 8]);
            }
#pragma unroll
            for (int ni = 0; ni < 4; ++ni) {
                int row = wn + ni * 16 + lm;
                bf16x8 bh = *(const bf16x8*)(&Bh[row * 40 + qd * 8]);
                bf16x8 bl = *(const bf16x8*)(&Bl[row * 40 + qd * 8]);
#pragma unroll
                for (int mi = 0; mi < 4; ++mi) {
                    f32x4 c = acc[mi][ni];
                    c = __builtin_amdgcn_mfma_f32_16x16x32_bf16(al[mi], bh, c, 0, 0, 0);
                    c = __builtin_amdgcn_mfma_f32_16x16x32_bf16(ah[mi], bl, c, 0, 0, 0);
                    c = __builtin_amdgcn_mfma_f32_16x16x32_bf16(ah[mi], bh, c, 0, 0, 0);
                    acc[mi][ni] = c;
                }
            }
        }
        __syncthreads();
    }

    // ---- epilogue: r-scale (convs), bias (z0), fp32 atomicAdd ----
#pragma unroll
    for (int ni = 0; ni < 4; ++ni) {
        int n = n0 + wn + ni * 16 + lm;
        if (n >= N) continue;
        float rs = 1.f;
        if (BMODE != 0) rs = rptr[(n >> lgS) * 3 + eA];
#pragma unroll
        for (int mi = 0; mi < 4; ++mi)
#pragma unroll
            for (int r = 0; r < 4; ++r) {
                int m = m0 + wm + mi * 16 + qd * 4 + r;
                if (m >= M) continue;
                float v = acc[mi][ni][r];
                if (BMODE != 0) v *= rs;
                if (BIAS && bz == 0) v += bias[m];
                if (TROUT) atomicAdd(&Cout[(size_t)n * M + m], v);
                else       atomicAdd(&Cout[(size_t)m * N + n], v);
            }
    }
}

// elementwise fp32 -> packed bf16x2 (optional relu)
__global__ __launch_bounds__(256)
void pack_kernel(const float* __restrict__ in, u32* __restrict__ outp,
                 int count, int relu)
{
    int i = blockIdx.x * 256 + threadIdx.x;
    if (i >= count) return;
    float v = in[i];
    if (relu) v = fmaxf(v, 0.f);
    outp[i] = packsplit(v);
}

// 2x2/2 maxpool + relu, fp32 in -> packed out
template<int RELU>
__global__ __launch_bounds__(256)
void pool_pack_kernel(const float* __restrict__ in, u32* __restrict__ outp,
                      int CB, int H, int W)
{
    int OH = H >> 1, OW = W >> 1;
    int total = CB * OH * OW;
    int i = blockIdx.x * 256 + threadIdx.x;
    if (i >= total) return;
    int ow = i % OW;
    int t = i / OW;
    int oh = t % OH;
    int cb = t / OH;
    const float* p = in + ((size_t)cb * H + (oh << 1)) * W + (ow << 1);
    float v = fmaxf(fmaxf(p[0], p[1]), fmaxf(p[W], p[W + 1]));
    if (RELU) v = fmaxf(v, 0.f);
    outp[i] = packsplit(v);
}

// conv5 fp32 [256,512,4,4] --relu+pool--> packed hT [b][1024]
__global__ __launch_bounds__(256)
void pool_flatten_pack_kernel(const float* __restrict__ in, u32* __restrict__ outp)
{
    int i = blockIdx.x * 256 + threadIdx.x;
    if (i >= 512 * 1024) return;
    int b = i >> 10;
    int f = i & 1023;
    int c = f >> 2, s = f & 3;
    int oh = s >> 1, ow = s & 1;
    const float* p = in + (((size_t)c * 512 + b) * 4 + (oh << 1)) * 4 + (ow << 1);
    float v = fmaxf(fmaxf(p[0], p[1]), fmaxf(p[4], p[5]));
    outp[i] = packsplit(fmaxf(v, 0.f));
}

// FC act: fp32 [Mt][Nt] --relu--> packed transposed [Nt][Mt]
__global__ __launch_bounds__(256)
void tp_pack_kernel(const float* __restrict__ in, u32* __restrict__ outp,
                    int Mt, int Nt)
{
    __shared__ float t[32][33];
    int tx = threadIdx.x & 31, ty = threadIdx.x >> 5;
    int mB = blockIdx.x << 5, nB = blockIdx.y << 5;
#pragma unroll
    for (int i = 0; i < 4; ++i) {
        int mm = ty + i * 8;
        t[mm][tx] = in[(size_t)(mB + mm) * Nt + nB + tx];
    }
    __syncthreads();
#pragma unroll
    for (int i = 0; i < 4; ++i) {
        int nn = ty + i * 8;
        float v = fmaxf(t[tx][nn], 0.f);
        outp[(size_t)(nB + nn) * Mt + mB + tx] = packsplit(v);
    }
}

extern "C" void kernel_launch(void* const* d_in, const int* in_sizes, int n_in,
                              void* d_out, int out_size, void* d_ws, size_t ws_size,
                              hipStream_t stream)
{
    const float* x    = (const float*)d_in[0];
    const float* dw1  = (const float*)d_in[1];
    const float* rw1  = (const float*)d_in[2];
    const float* rb1  = (const float*)d_in[3];
    const float* dw2  = (const float*)d_in[4];
    const float* rw2  = (const float*)d_in[5];
    const float* rb2  = (const float*)d_in[6];
    const float* dw3  = (const float*)d_in[7];
    const float* rw3  = (const float*)d_in[8];
    const float* rb3  = (const float*)d_in[9];
    const float* cw4  = (const float*)d_in[10];
    const float* cr4w = (const float*)d_in[11];
    const float* cr4b = (const float*)d_in[12];
    const float* cw5  = (const float*)d_in[13];
    const float* cr5w = (const float*)d_in[14];
    const float* cr5b = (const float*)d_in[15];
    const float* fw1  = (const float*)d_in[16];
    const float* fb1  = (const float*)d_in[17];
    const float* fw2  = (const float*)d_in[18];
    const float* fb2  = (const float*)d_in[19];
    const float* fw3  = (const float*)d_in[20];
    const float* fb3  = (const float*)d_in[21];
    float* out = (float*)d_out;

    // workspace (float units); total ~25.4M floats ~= 102 MB
    float* ws    = (float*)d_ws;
    float* r1    = ws;
    float* r2    = r1 + 1536;
    float* r3    = r2 + 1536;
    float* r4    = r3 + 1536;
    float* r5    = r4 + 1536;
    int2*  tabs  = (int2*)(ws + 8192);
    int2*  t1    = tabs;            // 96
    int2*  t2    = tabs + 1024;     // 1728
    int2*  t3    = tabs + 4096;     // 5184
    int2*  t4    = tabs + 12288;    // 10368
    int2*  t5    = tabs + 24576;    // 6912
    float* sdesc = ws + 8192 + 65536;
    // region: fp32 out-slab at front, per-layer weight planes at the back.
    // max simultaneous: fc2 (2,097,152 slab + 16,777,216 plane floats).
    const size_t REGION = 18874368;
    float* region = sdesc + 196608;
    float* slab   = region;
    u16*   regEnd = (u16*)(region + REGION);
    u32*   P1     = (u32*)(region + REGION);   // 3,145,728 u32
    u32*   P2     = P1 + 3145728;

    // per-layer plane pointers: whi at regEnd-2*Pe, wlo at regEnd-Pe (u16 units)
    u16 *w1h = regEnd - 2*(size_t)6144,     *w1l = regEnd - (size_t)6144;
    u16 *w2h = regEnd - 2*(size_t)331776,   *w2l = regEnd - (size_t)331776;
    u16 *w3h = regEnd - 2*(size_t)1990656,  *w3l = regEnd - (size_t)1990656;
    u16 *w4h = regEnd - 2*(size_t)2654208,  *w4l = regEnd - (size_t)2654208;
    u16 *w5h = regEnd - 2*(size_t)1769472,  *w5l = regEnd - (size_t)1769472;
    u16 *f1h = regEnd - 2*(size_t)4194304,  *f1l = regEnd - (size_t)4194304;
    u16 *f2h = regEnd - 2*(size_t)16777216, *f2l = regEnd - (size_t)16777216;
    u16 *f3h = regEnd - 2*(size_t)409600,   *f3l = regEnd - (size_t)409600;

    u32* xpk   = P1;
    u32* a1pk  = P2;
    u32* a2pk  = P1;
    u32* c3pk  = P2;
    u32* c4pk  = P1;
    u32* hTpk  = P2;
    u32* f1pkT = P1;
    u32* f2pkT = P2;

    const int B = 512;

    // ---- decode tables + input pack ----
    ktab_kernel<<<1, 256, 0, stream>>>(t1, 32, 27, 1024, 32);
    ktab_kernel<<<7, 256, 0, stream>>>(t2, 576, 576, 32768, 8);
    ktab_kernel<<<21, 256, 0, stream>>>(t3, 1728, 1728, 8192, 4);
    ktab_kernel<<<41, 256, 0, stream>>>(t4, 3456, 3456, 8192, 4);
    ktab_kernel<<<27, 256, 0, stream>>>(t5, 2304, 2304, 8192, 4);
    pack_kernel<<<6144, 256, 0, stream>>>(x, xpk, 1572864, 0);

    // ---- Layer 1: DyRes conv 3->64, s2 p1 -> slab [64, 131072] ----
    wsplit_kernel<<<24, 256, 0, stream>>>(dw1, w1h, w1l, 6144, 27, 32);
    stats_kernel<<<B * 3, 64, 0, stream>>>(x, sdesc, B, 3, 1024, 0, 1, 0);
    routing_kernel<<<B, 64, 0, stream>>>(sdesc, rw1, rb1, r1, 3, 1);
    hipMemsetAsync(slab, 0, (size_t)64 * 131072 * 4, stream);
    mgemm_kernel<2, 0, 0><<<dim3(1024, 1, 3), 256, 0, stream>>>(
        w1h, w1l, xpk, t1, r1, nullptr, slab, 64, 131072, 32, 32, 1, 3, B, 32, 32, 8, 4, 2);
    pool_pack_kernel<1><<<8192, 256, 0, stream>>>(slab, a1pk, 64 * 512, 16, 16);

    // ---- Layer 2: DyRes conv 64->192 -> slab [192, 32768] ----
    wsplit_kernel<<<1296, 256, 0, stream>>>(dw2, w2h, w2l, 331776, 576, 576);
    stats_kernel<<<B * 64, 64, 0, stream>>>(a1pk, sdesc, B, 64, 64, 1, 1, 1);
    routing_kernel<<<B, 64, 0, stream>>>(sdesc, rw2, rb2, r2, 64, 1);
    hipMemsetAsync(slab, 0, (size_t)192 * 32768 * 4, stream);
    mgemm_kernel<1, 0, 0><<<dim3(256, 2, 3), 256, 0, stream>>>(
        w2h, w2l, a1pk, t2, r2, nullptr, slab, 192, 32768, 576, 576, 1, 64, B, 8, 8, 6, 3, 1);
    pool_pack_kernel<1><<<6144, 256, 0, stream>>>(slab, a2pk, 192 * 512, 8, 8);

    // ---- Layer 3: DyRes conv 192->384 -> slab [384, 8192] ----
    wsplit_kernel<<<7776, 256, 0, stream>>>(dw3, w3h, w3l, 1990656, 1728, 1728);
    stats_kernel<<<B * 192, 64, 0, stream>>>(a2pk, sdesc, B, 192, 16, 1, 1, 1);
    routing_kernel<<<B, 64, 0, stream>>>(sdesc, rw3, rb3, r3, 192, 1);
    hipMemsetAsync(slab, 0, (size_t)384 * 8192 * 4, stream);
    mgemm_kernel<1, 0, 0><<<dim3(64, 3, 6), 256, 0, stream>>>(
        w3h, w3l, a2pk, t3, r3, nullptr, slab, 384, 8192, 1728, 864, 2, 192, B, 4, 4, 4, 2, 1);
    pack_kernel<<<12288, 256, 0, stream>>>(slab, c3pk, 3145728, 1);

    // ---- Layer 4: CondConv 384->256 -> slab [256, 8192] ----
    wsplit_kernel<<<10368, 256, 0, stream>>>(cw4, w4h, w4l, 2654208, 3456, 3456);
    stats_kernel<<<B * 384, 64, 0, stream>>>(c3pk, sdesc, B, 384, 16, 1, 0, 1);
    routing_kernel<<<B, 64, 0, stream>>>(sdesc, cr4w, cr4b, r4, 384, 0);
    hipMemsetAsync(slab, 0, (size_t)256 * 8192 * 4, stream);
    mgemm_kernel<1, 0, 0><<<dim3(64, 2, 6), 256, 0, stream>>>(
        w4h, w4l, c3pk, t4, r4, nullptr, slab, 256, 8192, 3456, 1728, 2, 384, B, 4, 4, 4, 2, 1);
    pack_kernel<<<8192, 256, 0, stream>>>(slab, c4pk, 2097152, 1);

    // ---- Layer 5: CondConv 256->256 -> slab [256, 8192] ----
    wsplit_kernel<<<6912, 256, 0, stream>>>(cw5, w5h, w5l, 1769472, 2304, 2304);
    stats_kernel<<<B * 256, 64, 0, stream>>>(c4pk, sdesc, B, 256, 16, 1, 0, 1);
    routing_kernel<<<B, 64, 0, stream>>>(sdesc, cr5w, cr5b, r5, 256, 0);
    hipMemsetAsync(slab, 0, (size_t)256 * 8192 * 4, stream);
    mgemm_kernel<1, 0, 0><<<dim3(64, 2, 6), 256, 0, stream>>>(
        w5h, w5l, c4pk, t5, r5, nullptr, slab, 256, 8192, 2304, 1152, 2, 256, B, 4, 4, 4, 2, 1);

    // ---- relu + pool + flatten -> packed hT [512][1024] ----
    pool_flatten_pack_kernel<<<2048, 256, 0, stream>>>(slab, hTpk);

    // ---- FC1: 1024 -> 4096 ----
    wsplit_kernel<<<16384, 256, 0, stream>>>(fw1, f1h, f1l, 4194304, 1024, 1024);
    hipMemsetAsync(slab, 0, (size_t)4096 * 512 * 4, stream);
    mgemm_kernel<0, 1, 0><<<dim3(4, 32, 8), 256, 0, stream>>>(
        f1h, f1l, hTpk, nullptr, nullptr, fb1, slab, 4096, 512, 1024, 128, 8, 0, 0, 0, 0, 0, 0, 0);
    tp_pack_kernel<<<dim3(128, 16), 256, 0, stream>>>(slab, f1pkT, 4096, 512);

    // ---- FC2: 4096 -> 4096 ----
    wsplit_kernel<<<65536, 256, 0, stream>>>(fw2, f2h, f2l, 16777216, 4096, 4096);
    hipMemsetAsync(slab, 0, (size_t)4096 * 512 * 4, stream);
    mgemm_kernel<0, 1, 0><<<dim3(4, 32, 8), 256, 0, stream>>>(
        f2h, f2l, f1pkT, nullptr, nullptr, fb2, slab, 4096, 512, 4096, 512, 8, 0, 0, 0, 0, 0, 0, 0);
    tp_pack_kernel<<<dim3(128, 16), 256, 0, stream>>>(slab, f2pkT, 4096, 512);

    // ---- FC3: 4096 -> 100 -> d_out [512, 100] ----
    wsplit_kernel<<<1600, 256, 0, stream>>>(fw3, f3h, f3l, 409600, 4096, 4096);
    hipMemsetAsync(out, 0, (size_t)512 * 100 * 4, stream);
    mgemm_kernel<0, 1, 1><<<dim3(4, 1, 32), 256, 0, stream>>>(
        f3h, f3l, f2pkT, nullptr, nullptr, fb3, out, 100, 512, 4096, 128, 32, 0, 0, 0, 0, 0, 0, 0);
}

// Round 2
// 1496.025 us; speedup vs baseline: 1.3073x; 1.3073x over previous
//
#include <hip/hip_runtime.h>
#include <math.h>

// ---------------------------------------------------------------------------
// DyRes/CondConv AlexNet forward. R9: conv GEMMs rebuilt as expert-fused,
// raw-barrier double-buffered pipeline (cgemm_kernel):
//  - LDS double-buffered, ONE asm barrier per K-step (lgkmcnt(0)+s_barrier,
//    NO vmcnt drain) so next-step global loads stay in flight across it.
//  - experts looped in-kernel with dual accumulator (acc per expert, folded
//    into accS with r[b,e]); L1/L2 plain stores (no atomics/memset), L3-L5
//    small split-K (z=2/4) with atomics for CU coverage.
//  - ktab dependent-load chain replaced by arithmetic (ci,kh,kw) decode.
//  - s_setprio(1) around MFMA cluster.
// FC layers keep the proven R7 mgemm (BMODE=0, 68 VGPR, split-K atomics).
// ---------------------------------------------------------------------------

typedef unsigned short u16;
typedef unsigned int u32;
typedef short bf16x8 __attribute__((ext_vector_type(8)));
typedef float f32x4 __attribute__((ext_vector_type(4)));

__device__ __forceinline__ u16 bf16_rne(float f) {
    u32 u = __float_as_uint(f);
    return (u16)((u + 0x7fffu + ((u >> 16) & 1u)) >> 16);
}
__device__ __forceinline__ u32 packsplit(float v) {
    u16 h = bf16_rne(v);
    float hf = __uint_as_float((u32)h << 16);
    u16 l = bf16_rne(v - hf);
    return ((u32)h << 16) | l;
}
__device__ __forceinline__ float unpackf(u32 p) {
    return __uint_as_float(p & 0xffff0000u) + __uint_as_float(p << 16);
}

// fp32 weights -> K-padded bf16 hi/lo planes (zero-padded beyond Kper)
__global__ __launch_bounds__(256)
void wsplit_kernel(const float* __restrict__ W, u16* __restrict__ whi,
                   u16* __restrict__ wlo, int total, int Kper, int Kpad)
{
    int idx = blockIdx.x * 256 + threadIdx.x;
    if (idx >= total) return;
    int r = idx / Kpad, k = idx - r * Kpad;
    float v = (k < Kper) ? W[(size_t)r * Kper + k] : 0.f;
    u16 h = bf16_rne(v);
    whi[idx] = h;
    wlo[idx] = bf16_rne(v - __uint_as_float((u32)h << 16));
}

__global__ __launch_bounds__(64)
void stats_kernel(const void* __restrict__ actv, float* __restrict__ s,
                  int Bsz, int C, int HW, int cbhw, int use_std, int packed)
{
    int idx = blockIdx.x;           // b*C + c
    int b = idx / C, c = idx - b * C;
    size_t base = (cbhw ? ((size_t)c * Bsz + b) : ((size_t)b * C + c)) * HW;
    int lane = threadIdx.x;
    float sum = 0.f, sq = 0.f;
    if (packed) {
        const u32* p = (const u32*)actv + base;
        for (int i = lane; i < HW; i += 64) { float v = unpackf(p[i]); sum += v; sq += v * v; }
    } else {
        const float* p = (const float*)actv + base;
        for (int i = lane; i < HW; i += 64) { float v = p[i]; sum += v; sq += v * v; }
    }
#pragma unroll
    for (int off = 32; off > 0; off >>= 1) {
        sum += __shfl_down(sum, off);
        sq  += __shfl_down(sq, off);
    }
    if (lane == 0) {
        float inv = 1.f / (float)HW;
        float mean = sum * inv;
        float var = sq * inv - mean * mean;
        float outv = mean;
        if (use_std) outv += sqrtf(fmaxf(var, 0.f));
        s[idx] = outv;
    }
}

__global__ __launch_bounds__(64)
void routing_kernel(const float* __restrict__ s, const float* __restrict__ rw,
                    const float* __restrict__ rb, float* __restrict__ r,
                    int C, int softmax_mode)
{
    int b = blockIdx.x;
    int lane = threadIdx.x;
    float d0 = 0.f, d1 = 0.f, d2 = 0.f;
    for (int c = lane; c < C; c += 64) {
        float sv = s[b * C + c];
        d0 += sv * rw[c];
        d1 += sv * rw[C + c];
        d2 += sv * rw[2 * C + c];
    }
#pragma unroll
    for (int off = 32; off > 0; off >>= 1) {
        d0 += __shfl_down(d0, off);
        d1 += __shfl_down(d1, off);
        d2 += __shfl_down(d2, off);
    }
    if (lane == 0) {
        d0 += rb[0]; d1 += rb[1]; d2 += rb[2];
        if (softmax_mode) {
            float mx = fmaxf(d0, fmaxf(d1, d2));
            float e0 = expf(d0 - mx), e1 = expf(d1 - mx), e2 = expf(d2 - mx);
            float inv = 1.f / (e0 + e1 + e2);
            r[b * 3 + 0] = e0 * inv;
            r[b * 3 + 1] = e1 * inv;
            r[b * 3 + 2] = e2 * inv;
        } else {
            r[b * 3 + 0] = 1.f / (1.f + expf(-d0));
            r[b * 3 + 1] = 1.f / (1.f + expf(-d1));
            r[b * 3 + 2] = 1.f / (1.f + expf(-d2));
        }
    }
}

// ---------------------------------------------------------------------------
// Expert-fused conv GEMM. Tile 128Mx128N, BK=32, 4 waves (2x2), 64x64/wave.
// BMODE 1: act [Ci,B,H,W]; BMODE 2: act [B,Ci,H,W]. z splits K (within each
// expert); e-loop inside with dual accumulator; fold accS += r[b,e]*acc.
// Pipeline: regs->ds_write(buf) -> issue next loads -> {lgkmcnt(0);s_barrier}
// (no vmcnt drain!) -> ds_read+MFMA(buf) -> toggle buf. One barrier/step.
// Epilogue: plain store if gridDim.z==1 else atomicAdd (Cout pre-zeroed).
// A-loads unconditional (OOB m rows read mapped ws garbage, discarded).
// ---------------------------------------------------------------------------
template<int BMODE>
__global__ __launch_bounds__(256, 2)
void cgemm_kernel(const u16* __restrict__ Whi, const u16* __restrict__ Wlo,
                  const u32* __restrict__ Bpk, const float* __restrict__ rptr,
                  float* __restrict__ Cout,
                  int M, int N, int Kper, int Kpad, int Kchunk,
                  int Ci, int Bsz, int H, int W, int lgS, int lgOW, int stride)
{
    __shared__ __align__(16) u16 Ah[2][128 * 40], Al[2][128 * 40];
    __shared__ __align__(16) u16 Bh[2][128 * 40], Bl[2][128 * 40];
    const int tid = threadIdx.x;
    const int n0 = blockIdx.x << 7, m0 = blockIdx.y << 7;
    const int kq0 = blockIdx.z * Kchunk;

    // staging coords
    const int rowA = tid >> 1, kh16 = (tid & 1) << 4;   // A: 2 thr/row
    const int nB = tid & 127, kOff = (tid >> 7) << 4;   // B: 16 k-elems/thread

    // n-side conv coords (k-independent)
    const int nn = n0 + nB;
    const int bB = nn >> lgS;
    const int sidx = nn & ((1 << lgS) - 1);
    const int ohs = (sidx >> lgOW) * stride - 1;
    const int ows = (sidx & ((1 << lgOW) - 1)) * stride - 1;
    const int chanStride = (BMODE == 2) ? H * W : Bsz * H * W;
    const long bOff = (BMODE == 2) ? (long)bB * Ci * H * W : (long)bB * H * W;
    const long nBase = bOff + (long)ohs * W + ows;

    const int lane = tid & 63, wv = tid >> 6;
    const int lm = lane & 15, qd = lane >> 4;
    const int wm = (wv & 1) << 6, wn = (wv >> 1) << 6;

    // routing scales r[b][e] for this thread's 4 ni columns
    float rsv[3][4];
#pragma unroll
    for (int ni = 0; ni < 4; ++ni) {
        int n = n0 + wn + ni * 16 + lm;
        int b = n >> lgS;
#pragma unroll
        for (int e = 0; e < 3; ++e) rsv[e][ni] = rptr[b * 3 + e];
    }

    f32x4 acc[4][4], accS[4][4];
#pragma unroll
    for (int i = 0; i < 4; ++i)
#pragma unroll
        for (int j = 0; j < 4; ++j) {
            acc[i][j]  = (f32x4){0.f, 0.f, 0.f, 0.f};
            accS[i][j] = (f32x4){0.f, 0.f, 0.f, 0.f};
        }

    const int mg = m0 + rowA;
    const int nkz = Kchunk >> 5;
    const int NS = 3 * nkz;

    // load-state (expert/k of the NEXT load to issue)
    int eL = 0, kL = kq0;
    // staged regs
    uint4 pA0, pA1, pA2, pA3;
    u32 pB[16];

    auto LOAD = [&]() {
        size_t aOff = ((size_t)(eL * M + mg)) * Kpad + kL + kh16;
        const u16* hp = Whi + aOff;
        const u16* lp = Wlo + aOff;
        pA0 = *(const uint4*)hp; pA1 = *(const uint4*)(hp + 8);
        pA2 = *(const uint4*)lp; pA3 = *(const uint4*)(lp + 8);
        int kb = kL + kOff;
#pragma unroll
        for (int j = 0; j < 16; ++j) {
            int k = kb + j;
            int ci = (int)((unsigned)k / 9u);
            int r9 = k - ci * 9;
            int kh = (int)(((unsigned)r9 * 11u) >> 5);
            int kw = r9 - kh * 3;
            int ih = ohs + kh, iw = ows + kw;
            u32 p = 0;
            if (k < Kper && (unsigned)ih < (unsigned)H && (unsigned)iw < (unsigned)W)
                p = Bpk[nBase + (long)ci * chanStride + kh * W + kw];
            pB[j] = p;
        }
    };
    auto ADV = [&]() {
        kL += 32;
        if (kL == kq0 + Kchunk) { kL = kq0; ++eL; }
    };
    auto STORE = [&](int buf) {
        *(uint4*)(&Ah[buf][rowA * 40 + kh16])     = pA0;
        *(uint4*)(&Ah[buf][rowA * 40 + kh16 + 8]) = pA1;
        *(uint4*)(&Al[buf][rowA * 40 + kh16])     = pA2;
        *(uint4*)(&Al[buf][rowA * 40 + kh16 + 8]) = pA3;
        u32 hw[8], lw[8];
#pragma unroll
        for (int j = 0; j < 8; ++j) {
            u32 p0 = pB[2 * j], p1 = pB[2 * j + 1];
            hw[j] = (p0 >> 16) | (p1 & 0xffff0000u);
            lw[j] = (p0 & 0xffffu) | (p1 << 16);
        }
        *(uint4*)(&Bh[buf][nB * 40 + kOff])     = make_uint4(hw[0], hw[1], hw[2], hw[3]);
        *(uint4*)(&Bh[buf][nB * 40 + kOff + 8]) = make_uint4(hw[4], hw[5], hw[6], hw[7]);
        *(uint4*)(&Bl[buf][nB * 40 + kOff])     = make_uint4(lw[0], lw[1], lw[2], lw[3]);
        *(uint4*)(&Bl[buf][nB * 40 + kOff + 8]) = make_uint4(lw[4], lw[5], lw[6], lw[7]);
    };
    auto COMPUTE = [&](int buf) {
        bf16x8 ah[4], al[4];
#pragma unroll
        for (int mi = 0; mi < 4; ++mi) {
            int row = wm + mi * 16 + lm;
            ah[mi] = *(const bf16x8*)(&Ah[buf][row * 40 + qd * 8]);
            al[mi] = *(const bf16x8*)(&Al[buf][row * 40 + qd * 8]);
        }
        __builtin_amdgcn_s_setprio(1);
#pragma unroll
        for (int ni = 0; ni < 4; ++ni) {
            int row = wn + ni * 16 + lm;
            bf16x8 bh = *(const bf16x8*)(&Bh[buf][row * 40 + qd * 8]);
            bf16x8 bl = *(const bf16x8*)(&Bl[buf][row * 40 + qd * 8]);
#pragma unroll
            for (int mi = 0; mi < 4; ++mi) {
                f32x4 c = acc[mi][ni];
                c = __builtin_amdgcn_mfma_f32_16x16x32_bf16(al[mi], bh, c, 0, 0, 0);
                c = __builtin_amdgcn_mfma_f32_16x16x32_bf16(ah[mi], bl, c, 0, 0, 0);
                c = __builtin_amdgcn_mfma_f32_16x16x32_bf16(ah[mi], bh, c, 0, 0, 0);
                acc[mi][ni] = c;
            }
        }
        __builtin_amdgcn_s_setprio(0);
    };

    LOAD(); ADV();
    int s = 0, buf = 0;
#pragma unroll
    for (int e = 0; e < 3; ++e) {
        for (int t = 0; t < nkz; ++t) {
            STORE(buf);                       // auto s_waitcnt on staged regs
            if (s + 1 < NS) { LOAD(); ADV(); }  // in flight across the barrier
            asm volatile("s_waitcnt lgkmcnt(0)\n\ts_barrier" ::: "memory");
            COMPUTE(buf);
            buf ^= 1; ++s;
        }
        // fold expert e into the routed sum
#pragma unroll
        for (int mi = 0; mi < 4; ++mi)
#pragma unroll
            for (int ni = 0; ni < 4; ++ni) {
                accS[mi][ni] += acc[mi][ni] * rsv[e][ni];
                acc[mi][ni] = (f32x4){0.f, 0.f, 0.f, 0.f};
            }
    }

    // ---- epilogue: plain store (z==1) or atomicAdd (split-K) ----
    const bool atom = (gridDim.z > 1);
#pragma unroll
    for (int ni = 0; ni < 4; ++ni) {
        int n = n0 + wn + ni * 16 + lm;
#pragma unroll
        for (int mi = 0; mi < 4; ++mi)
#pragma unroll
            for (int r = 0; r < 4; ++r) {
                int m = m0 + wm + mi * 16 + qd * 4 + r;
                if (m >= M) continue;
                float v = accS[mi][ni][r];
                if (atom) atomicAdd(&Cout[(size_t)m * N + n], v);
                else      Cout[(size_t)m * N + n] = v;
            }
    }
}

// ---------------------------------------------------------------------------
// FC GEMM (R7 form, BMODE=0 only): 128Mx128N tile, BK=32, split-K atomics.
// ---------------------------------------------------------------------------
template<int BMODE, int BIAS, int TROUT>
__global__ __launch_bounds__(256)
void mgemm_kernel(const u16* __restrict__ Whi, const u16* __restrict__ Wlo,
                  const u32* __restrict__ Bpk, const int2* __restrict__ ktab,
                  const float* __restrict__ rptr, const float* __restrict__ bias,
                  float* __restrict__ Cout,
                  int M, int N, int Kpad, int Kchunk, int zpe,
                  int Ci, int Bsz, int H, int W, int lgS, int lgOW, int stride)
{
    __shared__ __align__(16) u16 Ah[128 * 40], Al[128 * 40];  // rows m, pad to 40
    __shared__ __align__(16) u32 Bp[128 * 36];                // rows n, pad to 36
    const int tid = threadIdx.x;
    const int n0 = blockIdx.x << 7, m0 = blockIdx.y << 7;
    const int bz = blockIdx.z;
    const int eA = bz / zpe;
    const int kq0 = (bz - eA * zpe) * Kchunk;

    const int rowA = tid >> 1, kh16 = (tid & 1) << 4;
    const int nB = tid & 127, kOff = (tid >> 7) << 4;

    const int lane = tid & 63, wv = tid >> 6;
    const int lm = lane & 15, qd = lane >> 4;
    const int wm = (wv & 1) << 6, wn = (wv >> 1) << 6;

    f32x4 acc[4][4];
#pragma unroll
    for (int i = 0; i < 4; ++i)
#pragma unroll
        for (int j = 0; j < 4; ++j)
            acc[i][j] = (f32x4){0.f, 0.f, 0.f, 0.f};

    const size_t aRowBase = (size_t)eA * M;

    for (int kq = kq0; kq < kq0 + Kchunk; kq += 32) {
        {
            int mg = m0 + rowA;
            uint4 h0 = {0,0,0,0}, h1 = {0,0,0,0}, l0 = {0,0,0,0}, l1 = {0,0,0,0};
            if (mg < M) {
                const u16* hp = Whi + (aRowBase + mg) * Kpad + kq + kh16;
                const u16* lp = Wlo + (aRowBase + mg) * Kpad + kq + kh16;
                h0 = *(const uint4*)hp; h1 = *(const uint4*)(hp + 8);
                l0 = *(const uint4*)lp; l1 = *(const uint4*)(lp + 8);
            }
            *(uint4*)(&Ah[rowA * 40 + kh16])     = h0;
            *(uint4*)(&Ah[rowA * 40 + kh16 + 8]) = h1;
            *(uint4*)(&Al[rowA * 40 + kh16])     = l0;
            *(uint4*)(&Al[rowA * 40 + kh16 + 8]) = l1;
        }
        {
            const u32* bp = Bpk + (size_t)(n0 + nB) * Kpad + kq + kOff;
            uint4 q0 = *(const uint4*)bp;
            uint4 q1 = *(const uint4*)(bp + 4);
            uint4 q2 = *(const uint4*)(bp + 8);
            uint4 q3 = *(const uint4*)(bp + 12);
            *(uint4*)(&Bp[nB * 36 + kOff])      = q0;
            *(uint4*)(&Bp[nB * 36 + kOff + 4])  = q1;
            *(uint4*)(&Bp[nB * 36 + kOff + 8])  = q2;
            *(uint4*)(&Bp[nB * 36 + kOff + 12]) = q3;
        }
        __syncthreads();
        {
            bf16x8 ah[4], al[4];
#pragma unroll
            for (int mi = 0; mi < 4; ++mi) {
                int row = wm + mi * 16 + lm;
                ah[mi] = *(const bf16x8*)(&Ah[row * 40 + qd * 8]);
                al[mi] = *(const bf16x8*)(&Al[row * 40 + qd * 8]);
            }
#pragma unroll
            for (int ni = 0; ni < 4; ++ni) {
                int row = wn + ni * 16 + lm;
                const u32* bp = &Bp[row * 36 + qd * 8];
                uint4 p0 = *(const uint4*)bp;
                uint4 p1 = *(const uint4*)(bp + 4);
                union { u32 w[4]; bf16x8 v; } bh, bl;
                bh.w[0] = (p0.x >> 16) | (p0.y & 0xffff0000u);
                bl.w[0] = (p0.x & 0xffffu) | (p0.y << 16);
                bh.w[1] = (p0.z >> 16) | (p0.w & 0xffff0000u);
                bl.w[1] = (p0.z & 0xffffu) | (p0.w << 16);
                bh.w[2] = (p1.x >> 16) | (p1.y & 0xffff0000u);
                bl.w[2] = (p1.x & 0xffffu) | (p1.y << 16);
                bh.w[3] = (p1.z >> 16) | (p1.w & 0xffff0000u);
                bl.w[3] = (p1.z & 0xffffu) | (p1.w << 16);
#pragma unroll
                for (int mi = 0; mi < 4; ++mi) {
                    f32x4 c = acc[mi][ni];
                    c = __builtin_amdgcn_mfma_f32_16x16x32_bf16(al[mi], bh.v, c, 0, 0, 0);
                    c = __builtin_amdgcn_mfma_f32_16x16x32_bf16(ah[mi], bl.v, c, 0, 0, 0);
                    c = __builtin_amdgcn_mfma_f32_16x16x32_bf16(ah[mi], bh.v, c, 0, 0, 0);
                    acc[mi][ni] = c;
                }
            }
        }
        __syncthreads();
    }

#pragma unroll
    for (int ni = 0; ni < 4; ++ni) {
        int n = n0 + wn + ni * 16 + lm;
        if (n >= N) continue;
#pragma unroll
        for (int mi = 0; mi < 4; ++mi)
#pragma unroll
            for (int r = 0; r < 4; ++r) {
                int m = m0 + wm + mi * 16 + qd * 4 + r;
                if (m >= M) continue;
                float v = acc[mi][ni][r];
                if (BIAS && bz == 0) v += bias[m];
                if (TROUT) atomicAdd(&Cout[(size_t)n * M + m], v);
                else       atomicAdd(&Cout[(size_t)m * N + n], v);
            }
    }
}

// elementwise fp32 -> packed bf16x2 (optional relu)
__global__ __launch_bounds__(256)
void pack_kernel(const float* __restrict__ in, u32* __restrict__ outp,
                 int count, int relu)
{
    int i = blockIdx.x * 256 + threadIdx.x;
    if (i >= count) return;
    float v = in[i];
    if (relu) v = fmaxf(v, 0.f);
    outp[i] = packsplit(v);
}

// 2x2/2 maxpool + relu, fp32 in -> packed out
template<int RELU>
__global__ __launch_bounds__(256)
void pool_pack_kernel(const float* __restrict__ in, u32* __restrict__ outp,
                      int CB, int H, int W)
{
    int OH = H >> 1, OW = W >> 1;
    int total = CB * OH * OW;
    int i = blockIdx.x * 256 + threadIdx.x;
    if (i >= total) return;
    int ow = i % OW;
    int t = i / OW;
    int oh = t % OH;
    int cb = t / OH;
    const float* p = in + ((size_t)cb * H + (oh << 1)) * W + (ow << 1);
    float v = fmaxf(fmaxf(p[0], p[1]), fmaxf(p[W], p[W + 1]));
    if (RELU) v = fmaxf(v, 0.f);
    outp[i] = packsplit(v);
}

// conv5 fp32 [256,512,4,4] --relu+pool--> packed hT [b][1024]
__global__ __launch_bounds__(256)
void pool_flatten_pack_kernel(const float* __restrict__ in, u32* __restrict__ outp)
{
    int i = blockIdx.x * 256 + threadIdx.x;
    if (i >= 512 * 1024) return;
    int b = i >> 10;
    int f = i & 1023;
    int c = f >> 2, s = f & 3;
    int oh = s >> 1, ow = s & 1;
    const float* p = in + (((size_t)c * 512 + b) * 4 + (oh << 1)) * 4 + (ow << 1);
    float v = fmaxf(fmaxf(p[0], p[1]), fmaxf(p[4], p[5]));
    outp[i] = packsplit(fmaxf(v, 0.f));
}

// FC act: fp32 [Mt][Nt] --relu--> packed transposed [Nt][Mt]
__global__ __launch_bounds__(256)
void tp_pack_kernel(const float* __restrict__ in, u32* __restrict__ outp,
                    int Mt, int Nt)
{
    __shared__ float t[32][33];
    int tx = threadIdx.x & 31, ty = threadIdx.x >> 5;
    int mB = blockIdx.x << 5, nB = blockIdx.y << 5;
#pragma unroll
    for (int i = 0; i < 4; ++i) {
        int mm = ty + i * 8;
        t[mm][tx] = in[(size_t)(mB + mm) * Nt + nB + tx];
    }
    __syncthreads();
#pragma unroll
    for (int i = 0; i < 4; ++i) {
        int nn = ty + i * 8;
        float v = fmaxf(t[tx][nn], 0.f);
        outp[(size_t)(nB + nn) * Mt + mB + tx] = packsplit(v);
    }
}

extern "C" void kernel_launch(void* const* d_in, const int* in_sizes, int n_in,
                              void* d_out, int out_size, void* d_ws, size_t ws_size,
                              hipStream_t stream)
{
    const float* x    = (const float*)d_in[0];
    const float* dw1  = (const float*)d_in[1];
    const float* rw1  = (const float*)d_in[2];
    const float* rb1  = (const float*)d_in[3];
    const float* dw2  = (const float*)d_in[4];
    const float* rw2  = (const float*)d_in[5];
    const float* rb2  = (const float*)d_in[6];
    const float* dw3  = (const float*)d_in[7];
    const float* rw3  = (const float*)d_in[8];
    const float* rb3  = (const float*)d_in[9];
    const float* cw4  = (const float*)d_in[10];
    const float* cr4w = (const float*)d_in[11];
    const float* cr4b = (const float*)d_in[12];
    const float* cw5  = (const float*)d_in[13];
    const float* cr5w = (const float*)d_in[14];
    const float* cr5b = (const float*)d_in[15];
    const float* fw1  = (const float*)d_in[16];
    const float* fb1  = (const float*)d_in[17];
    const float* fw2  = (const float*)d_in[18];
    const float* fb2  = (const float*)d_in[19];
    const float* fw3  = (const float*)d_in[20];
    const float* fb3  = (const float*)d_in[21];
    float* out = (float*)d_out;

    // workspace (float units); layout unchanged from R7 (~102 MB)
    float* ws    = (float*)d_ws;
    float* r1    = ws;
    float* r2    = r1 + 1536;
    float* r3    = r2 + 1536;
    float* r4    = r3 + 1536;
    float* r5    = r4 + 1536;
    float* sdesc = ws + 8192 + 65536;
    const size_t REGION = 18874368;
    float* region = sdesc + 196608;
    float* slab   = region;
    u16*   regEnd = (u16*)(region + REGION);
    u32*   P1     = (u32*)(region + REGION);   // 3,145,728 u32
    u32*   P2     = P1 + 3145728;

    u16 *w1h = regEnd - 2*(size_t)6144,     *w1l = regEnd - (size_t)6144;
    u16 *w2h = regEnd - 2*(size_t)331776,   *w2l = regEnd - (size_t)331776;
    u16 *w3h = regEnd - 2*(size_t)1990656,  *w3l = regEnd - (size_t)1990656;
    u16 *w4h = regEnd - 2*(size_t)2654208,  *w4l = regEnd - (size_t)2654208;
    u16 *w5h = regEnd - 2*(size_t)1769472,  *w5l = regEnd - (size_t)1769472;
    u16 *f1h = regEnd - 2*(size_t)4194304,  *f1l = regEnd - (size_t)4194304;
    u16 *f2h = regEnd - 2*(size_t)16777216, *f2l = regEnd - (size_t)16777216;
    u16 *f3h = regEnd - 2*(size_t)409600,   *f3l = regEnd - (size_t)409600;

    u32* xpk   = P1;
    u32* a1pk  = P2;
    u32* a2pk  = P1;
    u32* c3pk  = P2;
    u32* c4pk  = P1;
    u32* hTpk  = P2;
    u32* f1pkT = P1;
    u32* f2pkT = P2;

    const int B = 512;

    // ---- input pack ----
    pack_kernel<<<6144, 256, 0, stream>>>(x, xpk, 1572864, 0);

    // ---- Layer 1: DyRes conv 3->64, s2 p1 -> slab [64, 131072] ----
    wsplit_kernel<<<24, 256, 0, stream>>>(dw1, w1h, w1l, 6144, 27, 32);
    stats_kernel<<<B * 3, 64, 0, stream>>>(x, sdesc, B, 3, 1024, 0, 1, 0);
    routing_kernel<<<B, 64, 0, stream>>>(sdesc, rw1, rb1, r1, 3, 1);
    cgemm_kernel<2><<<dim3(1024, 1, 1), 256, 0, stream>>>(
        w1h, w1l, xpk, r1, slab, 64, 131072, 27, 32, 32, 3, B, 32, 32, 8, 4, 2);
    pool_pack_kernel<1><<<8192, 256, 0, stream>>>(slab, a1pk, 64 * 512, 16, 16);

    // ---- Layer 2: DyRes conv 64->192 -> slab [192, 32768] ----
    wsplit_kernel<<<1296, 256, 0, stream>>>(dw2, w2h, w2l, 331776, 576, 576);
    stats_kernel<<<B * 64, 64, 0, stream>>>(a1pk, sdesc, B, 64, 64, 1, 1, 1);
    routing_kernel<<<B, 64, 0, stream>>>(sdesc, rw2, rb2, r2, 64, 1);
    cgemm_kernel<1><<<dim3(256, 2, 1), 256, 0, stream>>>(
        w2h, w2l, a1pk, r2, slab, 192, 32768, 576, 576, 576, 64, B, 8, 8, 6, 3, 1);
    pool_pack_kernel<1><<<6144, 256, 0, stream>>>(slab, a2pk, 192 * 512, 8, 8);

    // ---- Layer 3: DyRes conv 192->384 -> slab [384, 8192] ----
    wsplit_kernel<<<7776, 256, 0, stream>>>(dw3, w3h, w3l, 1990656, 1728, 1728);
    stats_kernel<<<B * 192, 64, 0, stream>>>(a2pk, sdesc, B, 192, 16, 1, 1, 1);
    routing_kernel<<<B, 64, 0, stream>>>(sdesc, rw3, rb3, r3, 192, 1);
    hipMemsetAsync(slab, 0, (size_t)384 * 8192 * 4, stream);
    cgemm_kernel<1><<<dim3(64, 3, 2), 256, 0, stream>>>(
        w3h, w3l, a2pk, r3, slab, 384, 8192, 1728, 1728, 864, 192, B, 4, 4, 4, 2, 1);
    pack_kernel<<<12288, 256, 0, stream>>>(slab, c3pk, 3145728, 1);

    // ---- Layer 4: CondConv 384->256 -> slab [256, 8192] ----
    wsplit_kernel<<<10368, 256, 0, stream>>>(cw4, w4h, w4l, 2654208, 3456, 3456);
    stats_kernel<<<B * 384, 64, 0, stream>>>(c3pk, sdesc, B, 384, 16, 1, 0, 1);
    routing_kernel<<<B, 64, 0, stream>>>(sdesc, cr4w, cr4b, r4, 384, 0);
    hipMemsetAsync(slab, 0, (size_t)256 * 8192 * 4, stream);
    cgemm_kernel<1><<<dim3(64, 2, 4), 256, 0, stream>>>(
        w4h, w4l, c3pk, r4, slab, 256, 8192, 3456, 3456, 864, 384, B, 4, 4, 4, 2, 1);
    pack_kernel<<<8192, 256, 0, stream>>>(slab, c4pk, 2097152, 1);

    // ---- Layer 5: CondConv 256->256 -> slab [256, 8192] ----
    wsplit_kernel<<<6912, 256, 0, stream>>>(cw5, w5h, w5l, 1769472, 2304, 2304);
    stats_kernel<<<B * 256, 64, 0, stream>>>(c4pk, sdesc, B, 256, 16, 1, 0, 1);
    routing_kernel<<<B, 64, 0, stream>>>(sdesc, cr5w, cr5b, r5, 256, 0);
    hipMemsetAsync(slab, 0, (size_t)256 * 8192 * 4, stream);
    cgemm_kernel<1><<<dim3(64, 2, 4), 256, 0, stream>>>(
        w5h, w5l, c4pk, r5, slab, 256, 8192, 2304, 2304, 576, 256, B, 4, 4, 4, 2, 1);

    // ---- relu + pool + flatten -> packed hT [512][1024] ----
    pool_flatten_pack_kernel<<<2048, 256, 0, stream>>>(slab, hTpk);

    // ---- FC1: 1024 -> 4096 ----
    wsplit_kernel<<<16384, 256, 0, stream>>>(fw1, f1h, f1l, 4194304, 1024, 1024);
    hipMemsetAsync(slab, 0, (size_t)4096 * 512 * 4, stream);
    mgemm_kernel<0, 1, 0><<<dim3(4, 32, 8), 256, 0, stream>>>(
        f1h, f1l, hTpk, nullptr, nullptr, fb1, slab, 4096, 512, 1024, 128, 8, 0, 0, 0, 0, 0, 0, 0);
    tp_pack_kernel<<<dim3(128, 16), 256, 0, stream>>>(slab, f1pkT, 4096, 512);

    // ---- FC2: 4096 -> 4096 ----
    wsplit_kernel<<<65536, 256, 0, stream>>>(fw2, f2h, f2l, 16777216, 4096, 4096);
    hipMemsetAsync(slab, 0, (size_t)4096 * 512 * 4, stream);
    mgemm_kernel<0, 1, 0><<<dim3(4, 32, 8), 256, 0, stream>>>(
        f2h, f2l, f1pkT, nullptr, nullptr, fb2, slab, 4096, 512, 4096, 512, 8, 0, 0, 0, 0, 0, 0, 0);
    tp_pack_kernel<<<dim3(128, 16), 256, 0, stream>>>(slab, f2pkT, 4096, 512);

    // ---- FC3: 4096 -> 100 -> d_out [512, 100] ----
    wsplit_kernel<<<1600, 256, 0, stream>>>(fw3, f3h, f3l, 409600, 4096, 4096);
    hipMemsetAsync(out, 0, (size_t)512 * 100 * 4, stream);
    mgemm_kernel<0, 1, 1><<<dim3(4, 1, 32), 256, 0, stream>>>(
        f3h, f3l, f2pkT, nullptr, nullptr, fb3, out, 100, 512, 4096, 128, 32, 0, 0, 0, 0, 0, 0, 0);
}

// Round 3
// 1473.337 us; speedup vs baseline: 1.3274x; 1.0154x over previous
//
#include <hip/hip_runtime.h>
#include <math.h>

// ---------------------------------------------------------------------------
// DyRes/CondConv AlexNet forward. R10: channels-last implicit GEMM for convs.
//  - Activations stored packed-u32 channels-last with zero halo:
//    act[b][h+1][w+1][ci]; weight-plane k-order permuted to (kh,kw,ci) at
//    wsplit. B staging = 1 cell decode + 4 unconditional dwordx4 loads
//    (halo removes all bounds masks). L1 (Ci=3) keeps the gather path.
//  - Conv outputs stored transposed C[n][m] = [B][H][W][Co] so the next
//    layer's input is already channels-last. pool/pack/stats rewritten.
//  - R9's raw-barrier double-buffered pipeline + expert fusion + setprio kept.
//  - XCD-aware blockIdx.x swizzle on conv gemms.
// FC layers keep the proven mgemm (BMODE=0, split-K atomics).
// ---------------------------------------------------------------------------

typedef unsigned short u16;
typedef unsigned int u32;
typedef short bf16x8 __attribute__((ext_vector_type(8)));
typedef float f32x4 __attribute__((ext_vector_type(4)));

__device__ __forceinline__ u16 bf16_rne(float f) {
    u32 u = __float_as_uint(f);
    return (u16)((u + 0x7fffu + ((u >> 16) & 1u)) >> 16);
}
__device__ __forceinline__ u32 packsplit(float v) {
    u16 h = bf16_rne(v);
    float hf = __uint_as_float((u32)h << 16);
    u16 l = bf16_rne(v - hf);
    return ((u32)h << 16) | l;
}
__device__ __forceinline__ float unpackf(u32 p) {
    return __uint_as_float(p & 0xffff0000u) + __uint_as_float(p << 16);
}
__device__ __forceinline__ int xcd_swz(int bid, int n) {
    // bijective when n % 8 == 0 (all conv grids satisfy this)
    if ((n & 7) != 0) return bid;
    int cpx = n >> 3;
    return (bid & 7) * cpx + (bid >> 3);
}

// fp32 weights -> K-padded bf16 hi/lo planes, source k-order (ci,kh,kw)
__global__ __launch_bounds__(256)
void wsplit_kernel(const float* __restrict__ W, u16* __restrict__ whi,
                   u16* __restrict__ wlo, int total, int Kper, int Kpad)
{
    int idx = blockIdx.x * 256 + threadIdx.x;
    if (idx >= total) return;
    int r = idx / Kpad, k = idx - r * Kpad;
    float v = (k < Kper) ? W[(size_t)r * Kper + k] : 0.f;
    u16 h = bf16_rne(v);
    whi[idx] = h;
    wlo[idx] = bf16_rne(v - __uint_as_float((u32)h << 16));
}

// fp32 weights -> bf16 hi/lo planes with k-order permuted to (kh,kw,ci)
__global__ __launch_bounds__(256)
void wsplit_cl_kernel(const float* __restrict__ W, u16* __restrict__ whi,
                      u16* __restrict__ wlo, int total, int Ci)
{
    int idx = blockIdx.x * 256 + threadIdx.x;
    if (idx >= total) return;
    int Kper = 9 * Ci;
    int r = idx / Kper, kp = idx - r * Kper;
    int cell = kp / Ci, ci = kp - cell * Ci;        // kp = cell*Ci + ci
    float v = W[(size_t)r * Kper + ci * 9 + cell];  // src k = ci*9 + kh*3 + kw
    u16 h = bf16_rne(v);
    whi[idx] = h;
    wlo[idx] = bf16_rne(v - __uint_as_float((u32)h << 16));
}

// stats over fp32 [B][C][HW] (layer-1 input only)
__global__ __launch_bounds__(64)
void stats_kernel(const float* __restrict__ actv, float* __restrict__ s,
                  int C, int HW, int use_std)
{
    int idx = blockIdx.x;           // b*C + c
    size_t base = (size_t)idx * HW;
    int lane = threadIdx.x;
    float sum = 0.f, sq = 0.f;
    const float* p = actv + base;
    for (int i = lane; i < HW; i += 64) { float v = p[i]; sum += v; sq += v * v; }
#pragma unroll
    for (int off = 32; off > 0; off >>= 1) {
        sum += __shfl_down(sum, off);
        sq  += __shfl_down(sq, off);
    }
    if (lane == 0) {
        float inv = 1.f / (float)HW;
        float mean = sum * inv;
        float var = sq * inv - mean * mean;
        float outv = mean;
        if (use_std) outv += sqrtf(fmaxf(var, 0.f));
        s[idx] = outv;
    }
}

// stats over packed channels-last halo'd act [B][H2][W2][C]; block=C, grid=B
__global__ __launch_bounds__(384)
void stats_cl_kernel(const u32* __restrict__ act, float* __restrict__ s,
                     int H2, int W2, int C, int use_std)
{
    int b = blockIdx.x, c = threadIdx.x;
    int Hin = H2 - 2, Win = W2 - 2;
    float sum = 0.f, sq = 0.f;
    for (int h = 0; h < Hin; ++h)
        for (int w = 0; w < Win; ++w) {
            float v = unpackf(act[(((size_t)b * H2 + h + 1) * W2 + w + 1) * C + c]);
            sum += v; sq += v * v;
        }
    float inv = 1.f / (float)(Hin * Win);
    float mean = sum * inv;
    float var = sq * inv - mean * mean;
    float outv = mean;
    if (use_std) outv += sqrtf(fmaxf(var, 0.f));
    s[b * C + c] = outv;
}

__global__ __launch_bounds__(64)
void routing_kernel(const float* __restrict__ s, const float* __restrict__ rw,
                    const float* __restrict__ rb, float* __restrict__ r,
                    int C, int softmax_mode)
{
    int b = blockIdx.x;
    int lane = threadIdx.x;
    float d0 = 0.f, d1 = 0.f, d2 = 0.f;
    for (int c = lane; c < C; c += 64) {
        float sv = s[b * C + c];
        d0 += sv * rw[c];
        d1 += sv * rw[C + c];
        d2 += sv * rw[2 * C + c];
    }
#pragma unroll
    for (int off = 32; off > 0; off >>= 1) {
        d0 += __shfl_down(d0, off);
        d1 += __shfl_down(d1, off);
        d2 += __shfl_down(d2, off);
    }
    if (lane == 0) {
        d0 += rb[0]; d1 += rb[1]; d2 += rb[2];
        if (softmax_mode) {
            float mx = fmaxf(d0, fmaxf(d1, d2));
            float e0 = expf(d0 - mx), e1 = expf(d1 - mx), e2 = expf(d2 - mx);
            float inv = 1.f / (e0 + e1 + e2);
            r[b * 3 + 0] = e0 * inv;
            r[b * 3 + 1] = e1 * inv;
            r[b * 3 + 2] = e2 * inv;
        } else {
            r[b * 3 + 0] = 1.f / (1.f + expf(-d0));
            r[b * 3 + 1] = 1.f / (1.f + expf(-d1));
            r[b * 3 + 2] = 1.f / (1.f + expf(-d2));
        }
    }
}

// ---------------------------------------------------------------------------
// Channels-last expert-fused conv GEMM (L2-L5). Tile 128Mx128N, BK=32,
// 4 waves. B from halo'd act [B][H2][W2][CI] packed u32, k-order (kh,kw,ci):
// 16-k fragment = 16 contiguous u32 -> 4 unconditional dwordx4 loads.
// Output transposed: C[n*M + m] (= [B][OH][OW][Co] channels-last fp32).
// Pipeline/e-fold/setprio identical to R9's cgemm.
// ---------------------------------------------------------------------------
template<int CI, int H2, int W2, int LGS, int LGOW>
__global__ __launch_bounds__(256, 2)
void cgemm_cl_kernel(const u16* __restrict__ Whi, const u16* __restrict__ Wlo,
                     const u32* __restrict__ Bpk, const float* __restrict__ rptr,
                     float* __restrict__ Cout, int M, int N, int Kper, int Kchunk)
{
    __shared__ __align__(16) u16 Ah[2][128 * 40], Al[2][128 * 40];
    __shared__ __align__(16) u16 Bh[2][128 * 40], Bl[2][128 * 40];
    const int tid = threadIdx.x;
    const int bx = xcd_swz(blockIdx.x, gridDim.x);
    const int n0 = bx << 7, m0 = blockIdx.y << 7;
    const int kq0 = blockIdx.z * Kchunk;

    const int rowA = tid >> 1, kh16 = (tid & 1) << 4;
    const int nB = tid & 127, kOff = (tid >> 7) << 4;

    const int nn = n0 + nB;
    const int bB = nn >> LGS;
    const int sidx = nn & ((1 << LGS) - 1);
    const int oh = sidx >> LGOW, ow = sidx & ((1 << LGOW) - 1);
    const long nBase = ((long)(bB * H2 + oh) * W2 + ow) * CI;

    const int lane = tid & 63, wv = tid >> 6;
    const int lm = lane & 15, qd = lane >> 4;
    const int wm = (wv & 1) << 6, wn = (wv >> 1) << 6;

    float rsv[3][4];
#pragma unroll
    for (int ni = 0; ni < 4; ++ni) {
        int n = n0 + wn + ni * 16 + lm;
        int b = n >> LGS;
#pragma unroll
        for (int e = 0; e < 3; ++e) rsv[e][ni] = rptr[b * 3 + e];
    }

    f32x4 acc[4][4], accS[4][4];
#pragma unroll
    for (int i = 0; i < 4; ++i)
#pragma unroll
        for (int j = 0; j < 4; ++j) {
            acc[i][j]  = (f32x4){0.f, 0.f, 0.f, 0.f};
            accS[i][j] = (f32x4){0.f, 0.f, 0.f, 0.f};
        }

    const int mg = m0 + rowA;
    const int nkz = Kchunk >> 5;
    const int NS = 3 * nkz;

    int eL = 0, kL = kq0;
    uint4 pA0, pA1, pA2, pA3;
    uint4 pQ0, pQ1, pQ2, pQ3;

    auto LOAD = [&]() {
        size_t aOff = ((size_t)(eL * M + mg)) * Kper + kL + kh16;
        const u16* hp = Whi + aOff;
        const u16* lp = Wlo + aOff;
        pA0 = *(const uint4*)hp; pA1 = *(const uint4*)(hp + 8);
        pA2 = *(const uint4*)lp; pA3 = *(const uint4*)(lp + 8);
        int k = kL + kOff;
        int cell = k / CI;               // CI constant -> folded
        int ci0 = k - cell * CI;
        int kh = (cell * 11) >> 5;
        int kw = cell - kh * 3;
        const u32* bp = Bpk + (nBase + (long)((kh * W2 + kw) * CI + ci0));
        pQ0 = *(const uint4*)bp;
        pQ1 = *(const uint4*)(bp + 4);
        pQ2 = *(const uint4*)(bp + 8);
        pQ3 = *(const uint4*)(bp + 12);
    };
    auto ADV = [&]() {
        kL += 32;
        if (kL == kq0 + Kchunk) { kL = kq0; ++eL; }
    };
    auto STORE = [&](int buf) {
        *(uint4*)(&Ah[buf][rowA * 40 + kh16])     = pA0;
        *(uint4*)(&Ah[buf][rowA * 40 + kh16 + 8]) = pA1;
        *(uint4*)(&Al[buf][rowA * 40 + kh16])     = pA2;
        *(uint4*)(&Al[buf][rowA * 40 + kh16 + 8]) = pA3;
        u32 qv[16] = {pQ0.x, pQ0.y, pQ0.z, pQ0.w, pQ1.x, pQ1.y, pQ1.z, pQ1.w,
                      pQ2.x, pQ2.y, pQ2.z, pQ2.w, pQ3.x, pQ3.y, pQ3.z, pQ3.w};
        u32 hw[8], lw[8];
#pragma unroll
        for (int j = 0; j < 8; ++j) {
            u32 p0 = qv[2 * j], p1 = qv[2 * j + 1];
            hw[j] = (p0 >> 16) | (p1 & 0xffff0000u);
            lw[j] = (p0 & 0xffffu) | (p1 << 16);
        }
        *(uint4*)(&Bh[buf][nB * 40 + kOff])     = make_uint4(hw[0], hw[1], hw[2], hw[3]);
        *(uint4*)(&Bh[buf][nB * 40 + kOff + 8]) = make_uint4(hw[4], hw[5], hw[6], hw[7]);
        *(uint4*)(&Bl[buf][nB * 40 + kOff])     = make_uint4(lw[0], lw[1], lw[2], lw[3]);
        *(uint4*)(&Bl[buf][nB * 40 + kOff + 8]) = make_uint4(lw[4], lw[5], lw[6], lw[7]);
    };
    auto COMPUTE = [&](int buf) {
        bf16x8 ah[4], al[4];
#pragma unroll
        for (int mi = 0; mi < 4; ++mi) {
            int row = wm + mi * 16 + lm;
            ah[mi] = *(const bf16x8*)(&Ah[buf][row * 40 + qd * 8]);
            al[mi] = *(const bf16x8*)(&Al[buf][row * 40 + qd * 8]);
        }
        __builtin_amdgcn_s_setprio(1);
#pragma unroll
        for (int ni = 0; ni < 4; ++ni) {
            int row = wn + ni * 16 + lm;
            bf16x8 bh = *(const bf16x8*)(&Bh[buf][row * 40 + qd * 8]);
            bf16x8 bl = *(const bf16x8*)(&Bl[buf][row * 40 + qd * 8]);
#pragma unroll
            for (int mi = 0; mi < 4; ++mi) {
                f32x4 c = acc[mi][ni];
                c = __builtin_amdgcn_mfma_f32_16x16x32_bf16(al[mi], bh, c, 0, 0, 0);
                c = __builtin_amdgcn_mfma_f32_16x16x32_bf16(ah[mi], bl, c, 0, 0, 0);
                c = __builtin_amdgcn_mfma_f32_16x16x32_bf16(ah[mi], bh, c, 0, 0, 0);
                acc[mi][ni] = c;
            }
        }
        __builtin_amdgcn_s_setprio(0);
    };

    LOAD(); ADV();
    int s = 0, buf = 0;
#pragma unroll
    for (int e = 0; e < 3; ++e) {
        for (int t = 0; t < nkz; ++t) {
            STORE(buf);
            if (s + 1 < NS) { LOAD(); ADV(); }
            asm volatile("s_waitcnt lgkmcnt(0)\n\ts_barrier" ::: "memory");
            COMPUTE(buf);
            buf ^= 1; ++s;
        }
#pragma unroll
        for (int mi = 0; mi < 4; ++mi)
#pragma unroll
            for (int ni = 0; ni < 4; ++ni) {
                accS[mi][ni] += acc[mi][ni] * rsv[e][ni];
                acc[mi][ni] = (f32x4){0.f, 0.f, 0.f, 0.f};
            }
    }

    const bool atom = (gridDim.z > 1);
#pragma unroll
    for (int ni = 0; ni < 4; ++ni) {
        int n = n0 + wn + ni * 16 + lm;
#pragma unroll
        for (int mi = 0; mi < 4; ++mi)
#pragma unroll
            for (int r = 0; r < 4; ++r) {
                int m = m0 + wm + mi * 16 + qd * 4 + r;
                if (m >= M) continue;
                float v = accS[mi][ni][r];
                if (atom) atomicAdd(&Cout[(size_t)n * M + m], v);
                else      Cout[(size_t)n * M + m] = v;
            }
    }
}

// ---------------------------------------------------------------------------
// Layer-1 conv GEMM (Ci=3, stride 2): R9 gather path, transposed output.
// act x packed [B][3][32][32].
// ---------------------------------------------------------------------------
__global__ __launch_bounds__(256, 2)
void cgemm_l1_kernel(const u16* __restrict__ Whi, const u16* __restrict__ Wlo,
                     const u32* __restrict__ Bpk, const float* __restrict__ rptr,
                     float* __restrict__ Cout, int M, int N)
{
    __shared__ __align__(16) u16 Ah[2][128 * 40], Al[2][128 * 40];
    __shared__ __align__(16) u16 Bh[2][128 * 40], Bl[2][128 * 40];
    const int tid = threadIdx.x;
    const int bx = xcd_swz(blockIdx.x, gridDim.x);
    const int n0 = bx << 7;
    const int Kper = 27, Kpad = 32;
    const int H = 32, W = 32;

    const int rowA = tid >> 1, kh16 = (tid & 1) << 4;
    const int nB = tid & 127, kOff = (tid >> 7) << 4;

    const int nn = n0 + nB;
    const int bB = nn >> 8;                 // S = 256
    const int sidx = nn & 255;
    const int ohs = (sidx >> 4) * 2 - 1;    // OW = 16, stride 2
    const int ows = (sidx & 15) * 2 - 1;
    const long nBase = (long)bB * 3072 + (long)ohs * W + ows;

    const int lane = tid & 63, wv = tid >> 6;
    const int lm = lane & 15, qd = lane >> 4;
    const int wm = (wv & 1) << 6, wn = (wv >> 1) << 6;

    float rsv[3][4];
#pragma unroll
    for (int ni = 0; ni < 4; ++ni) {
        int n = n0 + wn + ni * 16 + lm;
        int b = n >> 8;
#pragma unroll
        for (int e = 0; e < 3; ++e) rsv[e][ni] = rptr[b * 3 + e];
    }

    f32x4 acc[4][4], accS[4][4];
#pragma unroll
    for (int i = 0; i < 4; ++i)
#pragma unroll
        for (int j = 0; j < 4; ++j) {
            acc[i][j]  = (f32x4){0.f, 0.f, 0.f, 0.f};
            accS[i][j] = (f32x4){0.f, 0.f, 0.f, 0.f};
        }

    const int mg = rowA;   // single m-tile (M=64)
    int eL = 0;
    uint4 pA0, pA1, pA2, pA3;
    u32 pB[16];

    auto LOAD = [&]() {
        size_t aOff = ((size_t)(eL * M + mg)) * Kpad + kh16;
        const u16* hp = Whi + aOff;
        const u16* lp = Wlo + aOff;
        pA0 = *(const uint4*)hp; pA1 = *(const uint4*)(hp + 8);
        pA2 = *(const uint4*)lp; pA3 = *(const uint4*)(lp + 8);
#pragma unroll
        for (int j = 0; j < 16; ++j) {
            int k = kOff + j;
            int ci = (int)((unsigned)k / 9u);
            int r9 = k - ci * 9;
            int kh = (int)(((unsigned)r9 * 11u) >> 5);
            int kw = r9 - kh * 3;
            int ih = ohs + kh, iw = ows + kw;
            u32 p = 0;
            if (k < Kper && (unsigned)ih < (unsigned)H && (unsigned)iw < (unsigned)W)
                p = Bpk[nBase + (long)ci * 1024 + kh * W + kw];
            pB[j] = p;
        }
    };
    auto STORE = [&](int buf) {
        *(uint4*)(&Ah[buf][rowA * 40 + kh16])     = pA0;
        *(uint4*)(&Ah[buf][rowA * 40 + kh16 + 8]) = pA1;
        *(uint4*)(&Al[buf][rowA * 40 + kh16])     = pA2;
        *(uint4*)(&Al[buf][rowA * 40 + kh16 + 8]) = pA3;
        u32 hw[8], lw[8];
#pragma unroll
        for (int j = 0; j < 8; ++j) {
            u32 p0 = pB[2 * j], p1 = pB[2 * j + 1];
            hw[j] = (p0 >> 16) | (p1 & 0xffff0000u);
            lw[j] = (p0 & 0xffffu) | (p1 << 16);
        }
        *(uint4*)(&Bh[buf][nB * 40 + kOff])     = make_uint4(hw[0], hw[1], hw[2], hw[3]);
        *(uint4*)(&Bh[buf][nB * 40 + kOff + 8]) = make_uint4(hw[4], hw[5], hw[6], hw[7]);
        *(uint4*)(&Bl[buf][nB * 40 + kOff])     = make_uint4(lw[0], lw[1], lw[2], lw[3]);
        *(uint4*)(&Bl[buf][nB * 40 + kOff + 8]) = make_uint4(lw[4], lw[5], lw[6], lw[7]);
    };
    auto COMPUTE = [&](int buf) {
        bf16x8 ah[4], al[4];
#pragma unroll
        for (int mi = 0; mi < 4; ++mi) {
            int row = wm + mi * 16 + lm;
            ah[mi] = *(const bf16x8*)(&Ah[buf][row * 40 + qd * 8]);
            al[mi] = *(const bf16x8*)(&Al[buf][row * 40 + qd * 8]);
        }
        __builtin_amdgcn_s_setprio(1);
#pragma unroll
        for (int ni = 0; ni < 4; ++ni) {
            int row = wn + ni * 16 + lm;
            bf16x8 bh = *(const bf16x8*)(&Bh[buf][row * 40 + qd * 8]);
            bf16x8 bl = *(const bf16x8*)(&Bl[buf][row * 40 + qd * 8]);
#pragma unroll
            for (int mi = 0; mi < 4; ++mi) {
                f32x4 c = acc[mi][ni];
                c = __builtin_amdgcn_mfma_f32_16x16x32_bf16(al[mi], bh, c, 0, 0, 0);
                c = __builtin_amdgcn_mfma_f32_16x16x32_bf16(ah[mi], bl, c, 0, 0, 0);
                c = __builtin_amdgcn_mfma_f32_16x16x32_bf16(ah[mi], bh, c, 0, 0, 0);
                acc[mi][ni] = c;
            }
        }
        __builtin_amdgcn_s_setprio(0);
    };

    LOAD(); ++eL;
    int buf = 0;
#pragma unroll
    for (int e = 0; e < 3; ++e) {
        STORE(buf);
        if (e < 2) { LOAD(); ++eL; }
        asm volatile("s_waitcnt lgkmcnt(0)\n\ts_barrier" ::: "memory");
        COMPUTE(buf);
        buf ^= 1;
#pragma unroll
        for (int mi = 0; mi < 4; ++mi)
#pragma unroll
            for (int ni = 0; ni < 4; ++ni) {
                accS[mi][ni] += acc[mi][ni] * rsv[e][ni];
                acc[mi][ni] = (f32x4){0.f, 0.f, 0.f, 0.f};
            }
    }

#pragma unroll
    for (int ni = 0; ni < 4; ++ni) {
        int n = n0 + wn + ni * 16 + lm;
#pragma unroll
        for (int mi = 0; mi < 4; ++mi)
#pragma unroll
            for (int r = 0; r < 4; ++r) {
                int m = wm + mi * 16 + qd * 4 + r;
                if (m >= M) continue;
                Cout[(size_t)n * M + m] = accS[mi][ni][r];
            }
    }
}

// ---------------------------------------------------------------------------
// FC GEMM (BMODE=0 only): 128Mx128N tile, BK=32, split-K atomics. (R7 form)
// ---------------------------------------------------------------------------
template<int BIAS, int TROUT>
__global__ __launch_bounds__(256)
void mgemm_kernel(const u16* __restrict__ Whi, const u16* __restrict__ Wlo,
                  const u32* __restrict__ Bpk, const float* __restrict__ bias,
                  float* __restrict__ Cout,
                  int M, int N, int Kpad, int Kchunk)
{
    __shared__ __align__(16) u16 Ah[128 * 40], Al[128 * 40];
    __shared__ __align__(16) u32 Bp[128 * 36];
    const int tid = threadIdx.x;
    const int n0 = blockIdx.x << 7, m0 = blockIdx.y << 7;
    const int bz = blockIdx.z;
    const int kq0 = bz * Kchunk;

    const int rowA = tid >> 1, kh16 = (tid & 1) << 4;
    const int nB = tid & 127, kOff = (tid >> 7) << 4;

    const int lane = tid & 63, wv = tid >> 6;
    const int lm = lane & 15, qd = lane >> 4;
    const int wm = (wv & 1) << 6, wn = (wv >> 1) << 6;

    f32x4 acc[4][4];
#pragma unroll
    for (int i = 0; i < 4; ++i)
#pragma unroll
        for (int j = 0; j < 4; ++j)
            acc[i][j] = (f32x4){0.f, 0.f, 0.f, 0.f};

    for (int kq = kq0; kq < kq0 + Kchunk; kq += 32) {
        {
            int mg = m0 + rowA;
            uint4 h0 = {0,0,0,0}, h1 = {0,0,0,0}, l0 = {0,0,0,0}, l1 = {0,0,0,0};
            if (mg < M) {
                const u16* hp = Whi + (size_t)mg * Kpad + kq + kh16;
                const u16* lp = Wlo + (size_t)mg * Kpad + kq + kh16;
                h0 = *(const uint4*)hp; h1 = *(const uint4*)(hp + 8);
                l0 = *(const uint4*)lp; l1 = *(const uint4*)(lp + 8);
            }
            *(uint4*)(&Ah[rowA * 40 + kh16])     = h0;
            *(uint4*)(&Ah[rowA * 40 + kh16 + 8]) = h1;
            *(uint4*)(&Al[rowA * 40 + kh16])     = l0;
            *(uint4*)(&Al[rowA * 40 + kh16 + 8]) = l1;
        }
        {
            const u32* bp = Bpk + (size_t)(n0 + nB) * Kpad + kq + kOff;
            uint4 q0 = *(const uint4*)bp;
            uint4 q1 = *(const uint4*)(bp + 4);
            uint4 q2 = *(const uint4*)(bp + 8);
            uint4 q3 = *(const uint4*)(bp + 12);
            *(uint4*)(&Bp[nB * 36 + kOff])      = q0;
            *(uint4*)(&Bp[nB * 36 + kOff + 4])  = q1;
            *(uint4*)(&Bp[nB * 36 + kOff + 8])  = q2;
            *(uint4*)(&Bp[nB * 36 + kOff + 12]) = q3;
        }
        __syncthreads();
        {
            bf16x8 ah[4], al[4];
#pragma unroll
            for (int mi = 0; mi < 4; ++mi) {
                int row = wm + mi * 16 + lm;
                ah[mi] = *(const bf16x8*)(&Ah[row * 40 + qd * 8]);
                al[mi] = *(const bf16x8*)(&Al[row * 40 + qd * 8]);
            }
#pragma unroll
            for (int ni = 0; ni < 4; ++ni) {
                int row = wn + ni * 16 + lm;
                const u32* bp = &Bp[row * 36 + qd * 8];
                uint4 p0 = *(const uint4*)bp;
                uint4 p1 = *(const uint4*)(bp + 4);
                union { u32 w[4]; bf16x8 v; } bh, bl;
                bh.w[0] = (p0.x >> 16) | (p0.y & 0xffff0000u);
                bl.w[0] = (p0.x & 0xffffu) | (p0.y << 16);
                bh.w[1] = (p0.z >> 16) | (p0.w & 0xffff0000u);
                bl.w[1] = (p0.z & 0xffffu) | (p0.w << 16);
                bh.w[2] = (p1.x >> 16) | (p1.y & 0xffff0000u);
                bl.w[2] = (p1.x & 0xffffu) | (p1.y << 16);
                bh.w[3] = (p1.z >> 16) | (p1.w & 0xffff0000u);
                bl.w[3] = (p1.z & 0xffffu) | (p1.w << 16);
#pragma unroll
                for (int mi = 0; mi < 4; ++mi) {
                    f32x4 c = acc[mi][ni];
                    c = __builtin_amdgcn_mfma_f32_16x16x32_bf16(al[mi], bh.v, c, 0, 0, 0);
                    c = __builtin_amdgcn_mfma_f32_16x16x32_bf16(ah[mi], bl.v, c, 0, 0, 0);
                    c = __builtin_amdgcn_mfma_f32_16x16x32_bf16(ah[mi], bh.v, c, 0, 0, 0);
                    acc[mi][ni] = c;
                }
            }
        }
        __syncthreads();
    }

#pragma unroll
    for (int ni = 0; ni < 4; ++ni) {
        int n = n0 + wn + ni * 16 + lm;
        if (n >= N) continue;
#pragma unroll
        for (int mi = 0; mi < 4; ++mi)
#pragma unroll
            for (int r = 0; r < 4; ++r) {
                int m = m0 + wm + mi * 16 + qd * 4 + r;
                if (m >= M) continue;
                float v = acc[mi][ni][r];
                if (BIAS && bz == 0) v += bias[m];
                if (TROUT) atomicAdd(&Cout[(size_t)n * M + m], v);
                else       atomicAdd(&Cout[(size_t)m * N + n], v);
            }
    }
}

// elementwise fp32 -> packed bf16x2
__global__ __launch_bounds__(256)
void pack_kernel(const float* __restrict__ in, u32* __restrict__ outp, int count)
{
    int i = blockIdx.x * 256 + threadIdx.x;
    if (i >= count) return;
    outp[i] = packsplit(in[i]);
}

// 2x2/2 maxpool + relu: [B][Hin][Win][C] fp32 -> halo'd packed [B][OH+2][OW+2][C]
__global__ __launch_bounds__(256)
void pool_pack_cl_kernel(const float* __restrict__ in, u32* __restrict__ outp,
                         int Bn, int Hin, int Win, int C)
{
    int OH = Hin >> 1, OW = Win >> 1, H2 = OH + 2, W2 = OW + 2;
    int total = Bn * H2 * W2 * C;
    int i = blockIdx.x * 256 + threadIdx.x;
    if (i >= total) return;
    int c = i % C; int t = i / C;
    int w = t % W2; t /= W2;
    int h = t % H2; int b = t / H2;
    u32 pv = 0;
    if (h >= 1 && h <= OH && w >= 1 && w <= OW) {
        int oh = h - 1, ow = w - 1;
        const float* p = in + (((size_t)b * Hin + 2 * oh) * Win + 2 * ow) * C + c;
        size_t rs = (size_t)Win * C;
        float v = fmaxf(fmaxf(p[0], p[C]), fmaxf(p[rs], p[rs + C]));
        pv = packsplit(fmaxf(v, 0.f));
    }
    outp[i] = pv;
}

// relu (no pool): [B][Hin][Win][C] fp32 -> halo'd packed [B][Hin+2][Win+2][C]
__global__ __launch_bounds__(256)
void pack_cl_kernel(const float* __restrict__ in, u32* __restrict__ outp,
                    int Bn, int Hin, int Win, int C)
{
    int H2 = Hin + 2, W2 = Win + 2;
    int total = Bn * H2 * W2 * C;
    int i = blockIdx.x * 256 + threadIdx.x;
    if (i >= total) return;
    int c = i % C; int t = i / C;
    int w = t % W2; t /= W2;
    int h = t % H2; int b = t / H2;
    u32 pv = 0;
    if (h >= 1 && h <= Hin && w >= 1 && w <= Win) {
        float v = in[(((size_t)b * Hin + (h - 1)) * Win + (w - 1)) * C + c];
        pv = packsplit(fmaxf(v, 0.f));
    }
    outp[i] = pv;
}

// L5 out [B][4][4][256] fp32 --relu+pool--> packed hT[b][f], f = c*4+oh*2+ow
__global__ __launch_bounds__(256)
void pool_flatten_cl_kernel(const float* __restrict__ in, u32* __restrict__ outp)
{
    int i = blockIdx.x * 256 + threadIdx.x;
    if (i >= 512 * 1024) return;
    int b = i >> 10;
    int f = i & 1023;
    int c = f >> 2, sp = f & 3;
    int oh = sp >> 1, ow = sp & 1;
    const float* p = in + (((size_t)b * 4 + 2 * oh) * 4 + 2 * ow) * 256 + c;
    float v = fmaxf(fmaxf(p[0], p[256]), fmaxf(p[1024], p[1024 + 256]));
    outp[i] = packsplit(fmaxf(v, 0.f));
}

// FC act: fp32 [Mt][Nt] --relu--> packed transposed [Nt][Mt]
__global__ __launch_bounds__(256)
void tp_pack_kernel(const float* __restrict__ in, u32* __restrict__ outp,
                    int Mt, int Nt)
{
    __shared__ float t[32][33];
    int tx = threadIdx.x & 31, ty = threadIdx.x >> 5;
    int mB = blockIdx.x << 5, nB = blockIdx.y << 5;
#pragma unroll
    for (int i = 0; i < 4; ++i) {
        int mm = ty + i * 8;
        t[mm][tx] = in[(size_t)(mB + mm) * Nt + nB + tx];
    }
    __syncthreads();
#pragma unroll
    for (int i = 0; i < 4; ++i) {
        int nn = ty + i * 8;
        float v = fmaxf(t[tx][nn], 0.f);
        outp[(size_t)(nB + nn) * Mt + mB + tx] = packsplit(v);
    }
}

extern "C" void kernel_launch(void* const* d_in, const int* in_sizes, int n_in,
                              void* d_out, int out_size, void* d_ws, size_t ws_size,
                              hipStream_t stream)
{
    const float* x    = (const float*)d_in[0];
    const float* dw1  = (const float*)d_in[1];
    const float* rw1  = (const float*)d_in[2];
    const float* rb1  = (const float*)d_in[3];
    const float* dw2  = (const float*)d_in[4];
    const float* rw2  = (const float*)d_in[5];
    const float* rb2  = (const float*)d_in[6];
    const float* dw3  = (const float*)d_in[7];
    const float* rw3  = (const float*)d_in[8];
    const float* rb3  = (const float*)d_in[9];
    const float* cw4  = (const float*)d_in[10];
    const float* cr4w = (const float*)d_in[11];
    const float* cr4b = (const float*)d_in[12];
    const float* cw5  = (const float*)d_in[13];
    const float* cr5w = (const float*)d_in[14];
    const float* cr5b = (const float*)d_in[15];
    const float* fw1  = (const float*)d_in[16];
    const float* fb1  = (const float*)d_in[17];
    const float* fw2  = (const float*)d_in[18];
    const float* fb2  = (const float*)d_in[19];
    const float* fw3  = (const float*)d_in[20];
    const float* fb3  = (const float*)d_in[21];
    float* out = (float*)d_out;

    // ---- workspace (float units); total ~102 MB, layout as R7/R9 ----
    float* ws    = (float*)d_ws;
    float* r1    = ws;
    float* r2    = r1 + 1536;
    float* r3    = r2 + 1536;
    float* r4    = r3 + 1536;
    float* r5    = r4 + 1536;
    float* sdesc = ws + 8192 + 65536;
    const size_t REGION = 18874368;           // 75.5 MB region
    float* region = sdesc + 196608;
    float* slab   = region;                   // fp32 out-slab (front)
    u32*   a3u    = (u32*)(region + 4194304); // [512][6][6][384] = 7,077,888 u32
                                              // (middle: ends 45.1MB < planes)
    u16*   regEnd = (u16*)(region + REGION);
    u32*   P1     = (u32*)(region + REGION);  // 6,291,456 u32 (25.2 MB)

    // weight planes at region back (u16 units from regEnd)
    u16 *w1h = regEnd - 2*(size_t)6144,     *w1l = regEnd - (size_t)6144;
    u16 *w2h = regEnd - 2*(size_t)331776,   *w2l = regEnd - (size_t)331776;
    u16 *w3h = regEnd - 2*(size_t)1990656,  *w3l = regEnd - (size_t)1990656;
    u16 *w4h = regEnd - 2*(size_t)2654208,  *w4l = regEnd - (size_t)2654208;
    u16 *w5h = regEnd - 2*(size_t)1769472,  *w5l = regEnd - (size_t)1769472;
    u16 *f1h = regEnd - 2*(size_t)4194304,  *f1l = regEnd - (size_t)4194304;
    u16 *f2h = regEnd - 2*(size_t)16777216, *f2l = regEnd - (size_t)16777216;
    u16 *f3h = regEnd - 2*(size_t)409600,   *f3l = regEnd - (size_t)409600;

    // P-area time-multiplexed buffers (live ranges verified disjoint)
    u32* xpk   = P1;                 // [B][3][32][32]       1,572,864
    u32* a1    = P1;                 // [512][10][10][64]    3,276,800 (after L1)
    u32* a2    = P1;                 // [512][6][6][192]     3,538,944 (after L2)
    u32* a4    = P1;                 // [512][6][6][256]     4,718,592 (after L4)
    u32* hTpk  = P1;                 // [512][1024]            524,288 (after L5)
    u32* f1pkT = P1 + 1048576;       // [512][4096]          2,097,152
    u32* f2pkT = P1 + 3145728;       // [512][4096]          2,097,152

    const int B = 512;

    // ---- input pack ----
    pack_kernel<<<6144, 256, 0, stream>>>(x, xpk, 1572864);

    // ---- Layer 1: DyRes conv 3->64, s2 p1 -> slab [B][16][16][64] ----
    wsplit_kernel<<<24, 256, 0, stream>>>(dw1, w1h, w1l, 6144, 27, 32);
    stats_kernel<<<B * 3, 64, 0, stream>>>(x, sdesc, 3, 1024, 1);
    routing_kernel<<<B, 64, 0, stream>>>(sdesc, rw1, rb1, r1, 3, 1);
    cgemm_l1_kernel<<<dim3(1024, 1, 1), 256, 0, stream>>>(
        w1h, w1l, xpk, r1, slab, 64, 131072);
    pool_pack_cl_kernel<<<12800, 256, 0, stream>>>(slab, a1, B, 16, 16, 64);

    // ---- Layer 2: DyRes conv 64->192 -> slab [B][8][8][192] ----
    wsplit_cl_kernel<<<1296, 256, 0, stream>>>(dw2, w2h, w2l, 331776, 64);
    stats_cl_kernel<<<B, 64, 0, stream>>>(a1, sdesc, 10, 10, 64, 1);
    routing_kernel<<<B, 64, 0, stream>>>(sdesc, rw2, rb2, r2, 64, 1);
    cgemm_cl_kernel<64, 10, 10, 6, 3><<<dim3(256, 2, 1), 256, 0, stream>>>(
        w2h, w2l, a1, r2, slab, 192, 32768, 576, 576);
    pool_pack_cl_kernel<<<13824, 256, 0, stream>>>(slab, a2, B, 8, 8, 192);

    // ---- Layer 3: DyRes conv 192->384 -> slab [B][4][4][384] ----
    wsplit_cl_kernel<<<7776, 256, 0, stream>>>(dw3, w3h, w3l, 1990656, 192);
    stats_cl_kernel<<<B, 192, 0, stream>>>(a2, sdesc, 6, 6, 192, 1);
    routing_kernel<<<B, 64, 0, stream>>>(sdesc, rw3, rb3, r3, 192, 1);
    hipMemsetAsync(slab, 0, (size_t)8192 * 384 * 4, stream);
    cgemm_cl_kernel<192, 6, 6, 4, 2><<<dim3(64, 3, 2), 256, 0, stream>>>(
        w3h, w3l, a2, r3, slab, 384, 8192, 1728, 864);
    pack_cl_kernel<<<27648, 256, 0, stream>>>(slab, a3u, B, 4, 4, 384);

    // ---- Layer 4: CondConv 384->256 -> slab [B][4][4][256] ----
    wsplit_cl_kernel<<<10368, 256, 0, stream>>>(cw4, w4h, w4l, 2654208, 384);
    stats_cl_kernel<<<B, 384, 0, stream>>>(a3u, sdesc, 6, 6, 384, 0);
    routing_kernel<<<B, 64, 0, stream>>>(sdesc, cr4w, cr4b, r4, 384, 0);
    hipMemsetAsync(slab, 0, (size_t)8192 * 256 * 4, stream);
    cgemm_cl_kernel<384, 6, 6, 4, 2><<<dim3(64, 2, 4), 256, 0, stream>>>(
        w4h, w4l, a3u, r4, slab, 256, 8192, 3456, 864);
    pack_cl_kernel<<<18432, 256, 0, stream>>>(slab, a4, B, 4, 4, 256);

    // ---- Layer 5: CondConv 256->256 -> slab [B][4][4][256] ----
    wsplit_cl_kernel<<<6912, 256, 0, stream>>>(cw5, w5h, w5l, 1769472, 256);
    stats_cl_kernel<<<B, 256, 0, stream>>>(a4, sdesc, 6, 6, 256, 0);
    routing_kernel<<<B, 64, 0, stream>>>(sdesc, cr5w, cr5b, r5, 256, 0);
    hipMemsetAsync(slab, 0, (size_t)8192 * 256 * 4, stream);
    cgemm_cl_kernel<256, 6, 6, 4, 2><<<dim3(64, 2, 4), 256, 0, stream>>>(
        w5h, w5l, a4, r5, slab, 256, 8192, 2304, 576);

    // ---- relu + pool + flatten -> packed hT [512][1024] ----
    pool_flatten_cl_kernel<<<2048, 256, 0, stream>>>(slab, hTpk);

    // ---- FC1: 1024 -> 4096 ----
    wsplit_kernel<<<16384, 256, 0, stream>>>(fw1, f1h, f1l, 4194304, 1024, 1024);
    hipMemsetAsync(slab, 0, (size_t)4096 * 512 * 4, stream);
    mgemm_kernel<1, 0><<<dim3(4, 32, 8), 256, 0, stream>>>(
        f1h, f1l, hTpk, fb1, slab, 4096, 512, 1024, 128);
    tp_pack_kernel<<<dim3(128, 16), 256, 0, stream>>>(slab, f1pkT, 4096, 512);

    // ---- FC2: 4096 -> 4096 ----
    wsplit_kernel<<<65536, 256, 0, stream>>>(fw2, f2h, f2l, 16777216, 4096, 4096);
    hipMemsetAsync(slab, 0, (size_t)4096 * 512 * 4, stream);
    mgemm_kernel<1, 0><<<dim3(4, 32, 8), 256, 0, stream>>>(
        f2h, f2l, f1pkT, fb2, slab, 4096, 512, 4096, 512);
    tp_pack_kernel<<<dim3(128, 16), 256, 0, stream>>>(slab, f2pkT, 4096, 512);

    // ---- FC3: 4096 -> 100 -> d_out [512, 100] ----
    wsplit_kernel<<<1600, 256, 0, stream>>>(fw3, f3h, f3l, 409600, 4096, 4096);
    hipMemsetAsync(out, 0, (size_t)512 * 100 * 4, stream);
    mgemm_kernel<1, 1><<<dim3(4, 1, 32), 256, 0, stream>>>(
        f3h, f3l, f2pkT, fb3, out, 100, 512, 4096, 128);
}